// Round 6
// baseline (421.522 us; speedup 1.0000x reference)
//
#include <hip/hip_runtime.h>

typedef __attribute__((ext_vector_type(8))) _Float16 half8;
typedef __attribute__((ext_vector_type(4))) _Float16 half4;
typedef __attribute__((ext_vector_type(4))) float f32x4;

#define MFMA16(a, b, c) __builtin_amdgcn_mfma_f32_16x16x32_f16((a), (b), (c), 0, 0, 0)

// B=8, L=128, N=64, D=256, H=8, dk=32.  M = 65536 tokens.
// Token orders: LN = (b,l,n), NL = (b,n,l).

__device__ inline int map_ln_nl(int t) {   // (b,l,n) -> (b,n,l)
    return (t & ~8191) | ((t & 63) << 7) | ((t >> 6) & 127);
}
__device__ inline int map_nl_ln(int t) {   // (b,n,l) -> (b,l,n)
    return (t & ~8191) | ((t & 127) << 6) | ((t >> 7) & 63);
}

// ---------------- weight fp32 -> fp16 ----------------
// slots: 0=t_wq 1=t_wk 2=s_wk 3=t_wv 4=s_wv 5=W2(made elsewhere) 6=s_wd
__global__ __launch_bounds__(256) void cvt_weights(
    const float* __restrict__ w0, const float* __restrict__ w1,
    const float* __restrict__ w2, const float* __restrict__ w3,
    const float* __restrict__ w4, const float* __restrict__ w5,
    _Float16* __restrict__ out)
{
    const float* src[6] = {w0, w1, w2, w3, w4, w5};
    const int m = blockIdx.y;
    const int slot = (m < 5) ? m : 6;
    const int i = blockIdx.x * 256 + threadIdx.x;
    out[(size_t)slot * 65536 + i] = (_Float16)src[m][i];
}

// ---------------- W2 = s_wq @ t_wd (fp32 accum), b2 = s_wq @ t_bd ----------------
__global__ __launch_bounds__(256) void make_w2(
    const float* __restrict__ s_wq, const float* __restrict__ t_wd,
    const float* __restrict__ t_bd, _Float16* __restrict__ W2,
    float* __restrict__ b2)
{
    const int e = blockIdx.x;
    const int d = threadIdx.x;
    float acc = 0.0f;
    for (int c = 0; c < 256; ++c)
        acc = fmaf(s_wq[e * 256 + c], t_wd[c * 256 + d], acc);
    W2[e * 256 + d] = (_Float16)acc;
    if (d == 0) {
        float bb = 0.0f;
        for (int c = 0; c < 256; ++c) bb = fmaf(s_wq[e * 256 + c], t_bd[c], bb);
        b2[e] = bb;
    }
}

// ---------------- GEMM: C[M,*] = A[M,256] @ W[*,256]^T (+bias) ----------------
// 128x128 tile, BK=64, 4 waves (2x2), wave = 4x4 16x16x32 tiles.
// Reg-staged (T14): loads for tile k+1 issued to REGISTERS before MFMA(k);
// per step: barrier -> ds_write -> barrier.  Single LDS buffer, padded
// stride 68 halfs (136 B = 2 banks) -> <=2-way on both ds_write and ds_read.
// LDS 34 KB -> 3-4 blocks/CU (was 2 at 64 KB).
// Epilogue: C staged in LDS [128][132] fp16, stored as half8 full rows.
// Bijective XCD swizzle: col-blocks sharing an A-panel land on one XCD.
// DUAL: grid covers 512 weight rows; y<2 -> C0 with LN->NL map; y>=2 -> C1.
template <bool A_F32, int ROWMAP, bool DUAL, bool ADD_BIAS, bool OUT_F32>
__global__ __launch_bounds__(256, 3) void gemm16(
    const void* __restrict__ Ap, const _Float16* __restrict__ W,
    const float* __restrict__ bias, void* __restrict__ C0, void* __restrict__ C1)
{
    __shared__ __align__(16) _Float16 lds[17408];   // As[128][68] + Bs[128][68]
    _Float16* As = lds;
    _Float16* Bs = lds + 8704;

    const int tid  = threadIdx.x;
    const int lane = tid & 63;
    const int l15  = lane & 15;
    const int lhi  = lane >> 4;
    const int wid  = tid >> 6;
    const int nwg  = gridDim.x;
    const int wg   = (blockIdx.x & 7) * (nwg >> 3) + (blockIdx.x >> 3);
    const int y    = DUAL ? (wg & 3) : (wg & 1);
    const int x    = DUAL ? (wg >> 2) : (wg >> 1);
    const int m0   = x * 128;
    const int n0   = y * 128;
    const int wr   = (wid >> 1) * 64;
    const int wc   = (wid & 1) * 64;

    int rr[4], jj8[4];
#pragma unroll
    for (int i = 0; i < 4; ++i) {
        const int c = i * 256 + tid;       // chunk 0..1023
        rr[i]  = c >> 3;
        jj8[i] = (c & 7) * 8;              // straight column (elements)
    }

    f32x4 arA[4][2];   // fp32-A staging
    half8 arA16[4];    // fp16-A staging
    half8 brB[4];      // B staging

    auto loadA = [&](int kt) {
        const int k0 = kt * 64;
        if (A_F32) {
            const float* A = (const float*)Ap;
#pragma unroll
            for (int i = 0; i < 4; ++i) {
                const float* p = A + (size_t)(m0 + rr[i]) * 256 + k0 + jj8[i];
                arA[i][0] = *(const f32x4*)(p);
                arA[i][1] = *(const f32x4*)(p + 4);
            }
        } else {
            const _Float16* A = (const _Float16*)Ap;
#pragma unroll
            for (int i = 0; i < 4; ++i)
                arA16[i] = *(const half8*)(A + (size_t)(m0 + rr[i]) * 256 + k0 + jj8[i]);
        }
    };
    auto loadB = [&](int kt) {
        const int k0 = kt * 64;
#pragma unroll
        for (int i = 0; i < 4; ++i)
            brB[i] = *(const half8*)(W + (size_t)(n0 + rr[i]) * 256 + k0 + jj8[i]);
    };
    auto writeAB = [&]() {
#pragma unroll
        for (int i = 0; i < 4; ++i) {
            half8 h;
            if (A_F32) {
#pragma unroll
                for (int q = 0; q < 4; ++q) {
                    h[q]     = (_Float16)arA[i][0][q];
                    h[4 + q] = (_Float16)arA[i][1][q];
                }
            } else {
                h = arA16[i];
            }
            *(half8*)(As + rr[i] * 68 + jj8[i]) = h;
            *(half8*)(Bs + rr[i] * 68 + jj8[i]) = brB[i];
        }
    };

    f32x4 acc[4][4] = {};
    loadA(0);
    loadB(0);
    for (int kt = 0; kt < 4; ++kt) {
        __syncthreads();               // all waves done reading previous tile
        writeAB();                     // compiler waits vmcnt on reg deps
        __syncthreads();               // LDS visible
        if (kt < 3) { loadA(kt + 1); loadB(kt + 1); }   // hide under MFMA
#pragma unroll
        for (int kk = 0; kk < 2; ++kk) {
            half8 af[4], bf[4];
#pragma unroll
            for (int mi = 0; mi < 4; ++mi)
                af[mi] = *(const half8*)(As + (wr + mi * 16 + l15) * 68 + kk * 32 + lhi * 8);
#pragma unroll
            for (int nj = 0; nj < 4; ++nj)
                bf[nj] = *(const half8*)(Bs + (wc + nj * 16 + l15) * 68 + kk * 32 + lhi * 8);
#pragma unroll
            for (int mi = 0; mi < 4; ++mi)
#pragma unroll
                for (int nj = 0; nj < 4; ++nj)
                    acc[mi][nj] = MFMA16(af[mi], bf[nj], acc[mi][nj]);
        }
    }

    // ---------------- epilogue ----------------
    const bool hi = DUAL && (y >= 2);
    void* Cp = hi ? C1 : C0;
    const int cadj = hi ? 256 : 0;

    if (!OUT_F32) {
        // stage C-tile fp16 in LDS [128][132], then store full 256B rows
        __syncthreads();               // all MFMA LDS reads done
        _Float16* Cst = lds;
#pragma unroll
        for (int mi = 0; mi < 4; ++mi) {
#pragma unroll
            for (int nj = 0; nj < 4; ++nj) {
                const int col = wc + nj * 16 + l15;
                const float bv = ADD_BIAS ? bias[n0 + col - cadj] : 0.0f;
#pragma unroll
                for (int j = 0; j < 4; ++j)
                    Cst[(wr + mi * 16 + lhi * 4 + j) * 132 + col] =
                        (_Float16)(acc[mi][nj][j] + bv);
            }
        }
        __syncthreads();
#pragma unroll
        for (int it = 0; it < 8; ++it) {
            const int tr = wid * 32 + it * 4 + lhi;    // tile-local row
            const int grow = m0 + tr;
            int orow;
            if (DUAL)             orow = hi ? grow : map_ln_nl(grow);
            else if (ROWMAP == 1) orow = map_ln_nl(grow);
            else if (ROWMAP == 2) orow = map_nl_ln(grow);
            else                  orow = grow;
            const half8 hv = *(const half8*)(Cst + tr * 132 + l15 * 8);
            *(half8*)((_Float16*)Cp + (size_t)orow * 256 + (n0 - cadj) + l15 * 8) = hv;
        }
    } else {
        // fp32 output (final GEMM, ident rowmap): scalar path
#pragma unroll
        for (int mi = 0; mi < 4; ++mi) {
#pragma unroll
            for (int nj = 0; nj < 4; ++nj) {
                const int col = n0 + wc + nj * 16 + l15 - cadj;
                const float bv = ADD_BIAS ? bias[col] : 0.0f;
#pragma unroll
                for (int j = 0; j < 4; ++j) {
                    const int orow = m0 + wr + mi * 16 + lhi * 4 + j;
                    ((float*)Cp)[(size_t)orow * 256 + col] = acc[mi][nj][j] + bv;
                }
            }
        }
    }
}

// ---------------- temporal attention: per (b,n,h), seq = L = 128, NL layout ----------------
// Swapped QK^T: st = mfma(K_frag, Q_frag) -> lane holds S^T[k=rt*16+lhi*4+j][q=..+l15].
// Softmax reduce = in-lane + shfl_xor(16,32); P written as half4 (b64).
__global__ __launch_bounds__(256) void attn_temporal(
    const _Float16* __restrict__ Q, const _Float16* __restrict__ K,
    const _Float16* __restrict__ V, _Float16* __restrict__ O)
{
    __shared__ __align__(16) _Float16 Vt[32][136];   // V^T: [d][l]
    __shared__ __align__(16) _Float16 P[128][136];   // probabilities [q][k]

    const int tid  = threadIdx.x;
    const int lane = tid & 63;
    const int l15  = lane & 15;
    const int lhi  = lane >> 4;
    const int wid  = tid >> 6;
    const int bidx = blockIdx.x;
    const int h = bidx & 7;
    const int n = (bidx >> 3) & 63;
    const int b = bidx >> 9;
    const size_t base = ((size_t)(b * 64 + n) * 128) * 256 + (size_t)h * 32;

    // cooperative V transpose into LDS
    {
        const int l  = tid >> 1;
        const int dh = (tid & 1) * 16;
        const _Float16* srcp = V + base + (size_t)l * 256 + dh;
        half8 v0 = *(const half8*)(srcp);
        half8 v1 = *(const half8*)(srcp + 8);
#pragma unroll
        for (int j = 0; j < 8; ++j) {
            Vt[dh + j][l]     = v0[j];
            Vt[dh + 8 + j][l] = v1[j];
        }
    }
    __syncthreads();

    // S^T = K Q^T : wave owns q-cols [wid*32, wid*32+32), all 128 k-rows
    half8 qf[2];
#pragma unroll
    for (int ct = 0; ct < 2; ++ct)
        qf[ct] = *(const half8*)(Q + base +
                  (size_t)(wid * 32 + ct * 16 + l15) * 256 + lhi * 8);
    f32x4 st[2][8] = {};
#pragma unroll
    for (int rt = 0; rt < 8; ++rt) {
        half8 kf = *(const half8*)(K + base +
                    (size_t)(rt * 16 + l15) * 256 + lhi * 8);
#pragma unroll
        for (int ct = 0; ct < 2; ++ct)
            st[ct][rt] = MFMA16(kf, qf[ct], st[ct][rt]);
    }

    const float scale = 0.17677669529663687f;  // 1/sqrt(32)
#pragma unroll
    for (int ct = 0; ct < 2; ++ct) {
        const int q = wid * 32 + ct * 16 + l15;
        float m = st[ct][0][0];
#pragma unroll
        for (int rt = 0; rt < 8; ++rt)
#pragma unroll
            for (int j = 0; j < 4; ++j) m = fmaxf(m, st[ct][rt][j]);
        m = fmaxf(m, __shfl_xor(m, 16));
        m = fmaxf(m, __shfl_xor(m, 32));
        float sum = 0.0f;
#pragma unroll
        for (int rt = 0; rt < 8; ++rt)
#pragma unroll
            for (int j = 0; j < 4; ++j) {
                const float p = __expf((st[ct][rt][j] - m) * scale);
                st[ct][rt][j] = p;
                sum += p;
            }
        sum += __shfl_xor(sum, 16);
        sum += __shfl_xor(sum, 32);
        const float inv = 1.0f / sum;
#pragma unroll
        for (int rt = 0; rt < 8; ++rt) {
            half4 hv;
#pragma unroll
            for (int j = 0; j < 4; ++j) hv[j] = (_Float16)(st[ct][rt][j] * inv);
            *(half4*)(&P[q][rt * 16 + lhi * 4]) = hv;
        }
    }
    __syncthreads();

    // O = P V
    f32x4 o[2][2] = {};
#pragma unroll
    for (int ks = 0; ks < 4; ++ks) {
        half8 pa[2];
#pragma unroll
        for (int mi = 0; mi < 2; ++mi)
            pa[mi] = *(const half8*)(&P[wid * 32 + mi * 16 + l15][ks * 32 + lhi * 8]);
#pragma unroll
        for (int dt = 0; dt < 2; ++dt) {
            half8 vb = *(const half8*)(&Vt[dt * 16 + l15][ks * 32 + lhi * 8]);
#pragma unroll
            for (int mi = 0; mi < 2; ++mi)
                o[mi][dt] = MFMA16(pa[mi], vb, o[mi][dt]);
        }
    }
#pragma unroll
    for (int mi = 0; mi < 2; ++mi)
#pragma unroll
        for (int dt = 0; dt < 2; ++dt)
#pragma unroll
            for (int j = 0; j < 4; ++j)
                O[base + (size_t)(wid * 32 + mi * 16 + lhi * 4 + j) * 256 +
                  dt * 16 + l15] = (_Float16)o[mi][dt][j];
}

// ---------------- social attention: per (b,l,h), seq = N = 64, LN layout ----------------
__global__ __launch_bounds__(256) void attn_social(
    const _Float16* __restrict__ Q, const _Float16* __restrict__ K,
    const _Float16* __restrict__ V, _Float16* __restrict__ O)
{
    __shared__ __align__(16) _Float16 Vt[32][72];
    __shared__ __align__(16) _Float16 P[64][72];

    const int tid  = threadIdx.x;
    const int lane = tid & 63;
    const int l15  = lane & 15;
    const int lhi  = lane >> 4;
    const int wid  = tid >> 6;
    const int bidx = blockIdx.x;
    const int h = bidx & 7;
    const int l = (bidx >> 3) & 127;
    const int b = bidx >> 10;
    const size_t base = (((size_t)b * 128 + l) * 64) * 256 + (size_t)h * 32;

    {
        const int n  = tid >> 2;
        const int dq = (tid & 3) * 8;
        half8 v0 = *(const half8*)(V + base + (size_t)n * 256 + dq);
#pragma unroll
        for (int j = 0; j < 8; ++j) Vt[dq + j][n] = v0[j];
    }
    __syncthreads();

    // S^T : wave owns q-cols [wid*16, wid*16+16), all 64 k-rows
    half8 qf = *(const half8*)(Q + base + (size_t)(wid * 16 + l15) * 256 + lhi * 8);
    f32x4 st[4] = {};
#pragma unroll
    for (int rt = 0; rt < 4; ++rt) {
        half8 kf = *(const half8*)(K + base + (size_t)(rt * 16 + l15) * 256 + lhi * 8);
        st[rt] = MFMA16(kf, qf, st[rt]);
    }

    const float scale = 0.17677669529663687f;
    {
        const int q = wid * 16 + l15;
        float m = st[0][0];
#pragma unroll
        for (int rt = 0; rt < 4; ++rt)
#pragma unroll
            for (int j = 0; j < 4; ++j) m = fmaxf(m, st[rt][j]);
        m = fmaxf(m, __shfl_xor(m, 16));
        m = fmaxf(m, __shfl_xor(m, 32));
        float sum = 0.0f;
#pragma unroll
        for (int rt = 0; rt < 4; ++rt)
#pragma unroll
            for (int j = 0; j < 4; ++j) {
                const float p = __expf((st[rt][j] - m) * scale);
                st[rt][j] = p;
                sum += p;
            }
        sum += __shfl_xor(sum, 16);
        sum += __shfl_xor(sum, 32);
        const float inv = 1.0f / sum;
#pragma unroll
        for (int rt = 0; rt < 4; ++rt) {
            half4 hv;
#pragma unroll
            for (int j = 0; j < 4; ++j) hv[j] = (_Float16)(st[rt][j] * inv);
            *(half4*)(&P[q][rt * 16 + lhi * 4]) = hv;
        }
    }
    __syncthreads();

    f32x4 o[2] = {};
#pragma unroll
    for (int ks = 0; ks < 2; ++ks) {
        half8 pa = *(const half8*)(&P[wid * 16 + l15][ks * 32 + lhi * 8]);
#pragma unroll
        for (int dt = 0; dt < 2; ++dt) {
            half8 vb = *(const half8*)(&Vt[dt * 16 + l15][ks * 32 + lhi * 8]);
            o[dt] = MFMA16(pa, vb, o[dt]);
        }
    }
#pragma unroll
    for (int dt = 0; dt < 2; ++dt)
#pragma unroll
        for (int j = 0; j < 4; ++j)
            O[base + (size_t)(wid * 16 + lhi * 4 + j) * 256 + dt * 16 + l15] =
                (_Float16)o[dt][j];
}

// ---------------- host launch ----------------
extern "C" void kernel_launch(void* const* d_in, const int* in_sizes, int n_in,
                              void* d_out, int out_size, void* d_ws, size_t ws_size,
                              hipStream_t stream)
{
    const float* q    = (const float*)d_in[0];
    const float* k    = (const float*)d_in[1];
    const float* v    = (const float*)d_in[2];
    const float* t_wq = (const float*)d_in[3];
    const float* t_wk = (const float*)d_in[4];
    const float* t_wv = (const float*)d_in[5];
    const float* t_wd = (const float*)d_in[6];
    const float* t_bd = (const float*)d_in[7];
    const float* s_wq = (const float*)d_in[8];
    const float* s_wk = (const float*)d_in[9];
    const float* s_wv = (const float*)d_in[10];
    const float* s_wd = (const float*)d_in[11];
    const float* s_bd = (const float*)d_in[12];

    // workspace: 7 fp16 weight slots + b2 (fp32) + 6 activation slots (32 MB)
    _Float16* Wb = (_Float16*)d_ws;
    float* b2 = (float*)(Wb + 7 * 65536);
    const size_t SLOT = (size_t)65536 * 256;
    _Float16* S0 = (_Float16*)(b2 + 256);
    _Float16* S1 = S0 + SLOT;
    _Float16* S2 = S0 + 2 * SLOT;
    _Float16* S3 = S0 + 3 * SLOT;
    _Float16* S4 = S0 + 4 * SLOT;
    _Float16* S5 = S0 + 5 * SLOT;

    cvt_weights<<<dim3(256, 6), 256, 0, stream>>>(
        t_wq, t_wk, s_wk, t_wv, s_wv, s_wd, Wb);
    make_w2<<<256, 256, 0, stream>>>(s_wq, t_wd, t_bd, Wb + 5 * 65536, b2);

    const dim3 gb(256);
    // Qt(NL) = q @ t_wq^T -> S1   (fp32 A read directly)
    gemm16<true, 1, false, false, false><<<1024, gb, 0, stream>>>(
        q, Wb + 0 * 65536, nullptr, S1, nullptr);
    // Kt(NL) -> S2, Ks(LN) -> S3  (dual over [t_wk; s_wk])
    gemm16<true, 1, true, false, false><<<2048, gb, 0, stream>>>(
        k, Wb + 1 * 65536, nullptr, S2, S3);
    // Vt(NL) -> S4, Vs(LN) -> S5
    gemm16<true, 1, true, false, false><<<2048, gb, 0, stream>>>(
        v, Wb + 3 * 65536, nullptr, S4, S5);

    attn_temporal<<<4096, gb, 0, stream>>>(S1, S2, S4, S0);   // Ot(NL) -> S0

    // Qs(LN) = Ot @ W2^T + b2 -> S1
    gemm16<false, 2, false, true, false><<<1024, gb, 0, stream>>>(
        S0, Wb + 5 * 65536, b2, S1, nullptr);

    attn_social<<<8192, gb, 0, stream>>>(S1, S3, S5, S2);     // Os(LN) -> S2

    gemm16<false, 0, false, true, true><<<1024, gb, 0, stream>>>(
        S2, Wb + 6 * 65536, s_bd, d_out, nullptr);

    (void)in_sizes; (void)n_in; (void)out_size; (void)ws_size;
}

// Round 7
// 289.199 us; speedup vs baseline: 1.4576x; 1.4576x over previous
//
#include <hip/hip_runtime.h>

typedef __attribute__((ext_vector_type(8))) _Float16 half8;
typedef __attribute__((ext_vector_type(4))) _Float16 half4;
typedef __attribute__((ext_vector_type(4))) float f32x4;

#define MFMA16(a, b, c) __builtin_amdgcn_mfma_f32_16x16x32_f16((a), (b), (c), 0, 0, 0)

// counted waitcnt + raw barrier (asm, memory-clobbered: no mem op crosses)
#define WAITV(N) asm volatile("s_waitcnt vmcnt(" #N ") lgkmcnt(0)" ::: "memory")
#define SBAR()   asm volatile("s_barrier" ::: "memory")

// B=8, L=128, N=64, D=256, H=8, dk=32.  M = 65536 tokens.
// Token orders: LN = (b,l,n), NL = (b,n,l).

__device__ inline int map_ln_nl(int t) {   // (b,l,n) -> (b,n,l)
    return (t & ~8191) | ((t & 63) << 7) | ((t >> 6) & 127);
}
__device__ inline int map_nl_ln(int t) {   // (b,n,l) -> (b,l,n)
    return (t & ~8191) | ((t & 127) << 6) | ((t >> 7) & 63);
}

typedef const __attribute__((address_space(1))) unsigned int guint;
typedef __attribute__((address_space(3))) unsigned int luint;
__device__ inline void gld16(const _Float16* g, _Float16* l) {
    __builtin_amdgcn_global_load_lds((guint*)g, (luint*)l, 16, 0, 0);
}

// ---------------- weight fp32 -> fp16 ----------------
// slots: 0=t_wq 1=t_wk 2=s_wk 3=t_wv 4=s_wv 5=W2(made elsewhere) 6=s_wd
__global__ __launch_bounds__(256) void cvt_weights(
    const float* __restrict__ w0, const float* __restrict__ w1,
    const float* __restrict__ w2, const float* __restrict__ w3,
    const float* __restrict__ w4, const float* __restrict__ w5,
    _Float16* __restrict__ out)
{
    const float* src[6] = {w0, w1, w2, w3, w4, w5};
    const int m = blockIdx.y;
    const int slot = (m < 5) ? m : 6;
    const int i = blockIdx.x * 256 + threadIdx.x;
    out[(size_t)slot * 65536 + i] = (_Float16)src[m][i];
}

// ---------------- W2 = s_wq @ t_wd (fp32 accum), b2 = s_wq @ t_bd ----------------
__global__ __launch_bounds__(256) void make_w2(
    const float* __restrict__ s_wq, const float* __restrict__ t_wd,
    const float* __restrict__ t_bd, _Float16* __restrict__ W2,
    float* __restrict__ b2)
{
    const int e = blockIdx.x;
    const int d = threadIdx.x;
    float acc = 0.0f;
    for (int c = 0; c < 256; ++c)
        acc = fmaf(s_wq[e * 256 + c], t_wd[c * 256 + d], acc);
    W2[e * 256 + d] = (_Float16)acc;
    if (d == 0) {
        float bb = 0.0f;
        for (int c = 0; c < 256; ++c) bb = fmaf(s_wq[e * 256 + c], t_bd[c], bb);
        b2[e] = bb;
    }
}

// ---------------- GEMM: C[M,*] = A[M,256] @ W[*,256]^T (+bias) ----------------
// 256x256 tile, BK=64, 8 waves (2x4), wave = 128x64 = 8x4 16x16x32 tiles.
// Pipeline per K-step: stage(t+1) -> s_waitcnt vmcnt(COUNTED) lgkmcnt(0) ->
// s_barrier -> MFMA -> s_barrier [-> writeA(t+1) for fp32-A].  Loads for
// tile t+1 stay in flight across both barriers (T3/T4); vmcnt(0) only at
// the last step.  LDS 128 KB = 2buf x (A 256x64 + B 256x64) fp16, linear
// rows with XOR pre-swizzled source (R5-proven, 0 conflicts).
// Bijective XCD swizzle.  DUAL: y=0 -> C0 (LN->NL map), y=1 -> C1 ident.
template <bool A_F32, int ROWMAP, bool DUAL, bool ADD_BIAS, bool OUT_F32>
__global__ __launch_bounds__(512, 2) void gemm16(
    const void* __restrict__ Ap, const _Float16* __restrict__ W,
    const float* __restrict__ bias, void* __restrict__ C0, void* __restrict__ C1)
{
    __shared__ __align__(16) _Float16 lds[65536];   // 128 KB

    const int tid  = threadIdx.x;
    const int lane = tid & 63;
    const int l15  = lane & 15;
    const int lhi  = lane >> 4;
    const int wid  = tid >> 6;
    const int nwg  = gridDim.x;
    const int wg   = (blockIdx.x & 7) * (nwg >> 3) + (blockIdx.x >> 3);
    const int y    = DUAL ? (wg & 1) : 0;
    const int x    = DUAL ? (wg >> 1) : wg;
    const int m0   = x * 256;
    const int n0   = y * 256;
    const int wr   = (wid >> 2) * 128;   // wave row (2 row-groups)
    const int wc   = (wid & 3) * 64;     // wave col (4 col-groups)

    // staging chunks: 2048 per operand (256 rows x 8 chunks of 8 halfs)
    int rr[4], cc[4];
#pragma unroll
    for (int i = 0; i < 4; ++i) {
        const int c = i * 512 + tid;
        const int r = c >> 3;
        rr[i] = r;
        cc[i] = ((c & 7) ^ (r & 7)) * 8;   // pre-swizzled column
    }

    f32x4 arA[4][2];   // fp32-A staging regs

    auto issueA32 = [&](int kt) {
        const float* A = (const float*)Ap;
        const int k0 = kt * 64;
#pragma unroll
        for (int i = 0; i < 4; ++i) {
            const float* p = A + (size_t)(m0 + rr[i]) * 256 + k0 + cc[i];
            arA[i][0] = *(const f32x4*)(p);
            arA[i][1] = *(const f32x4*)(p + 4);
        }
    };
    auto writeA32 = [&](int buf) {
        _Float16* Ad = lds + buf * 16384;
#pragma unroll
        for (int i = 0; i < 4; ++i) {
            half8 h;
#pragma unroll
            for (int q = 0; q < 4; ++q) {
                h[q]     = (_Float16)arA[i][0][q];
                h[4 + q] = (_Float16)arA[i][1][q];
            }
            *(half8*)(Ad + (i * 512 + tid) * 8) = h;
        }
    };
    auto stageA16 = [&](int buf, int kt) {
        const _Float16* A = (const _Float16*)Ap;
        _Float16* Ad = lds + buf * 16384;
        const int k0 = kt * 64;
#pragma unroll
        for (int i = 0; i < 4; ++i)
            gld16(A + (size_t)(m0 + rr[i]) * 256 + k0 + cc[i],
                  Ad + (i * 512 + tid) * 8);
    };
    auto stageB = [&](int buf, int kt) {
        _Float16* Bd = lds + 32768 + buf * 16384;
        const int k0 = kt * 64;
#pragma unroll
        for (int i = 0; i < 4; ++i)
            gld16(W + (size_t)(n0 + rr[i]) * 256 + k0 + cc[i],
                  Bd + (i * 512 + tid) * 8);
    };

    f32x4 acc[8][4] = {};

    // prologue: tile 0
    if (A_F32) { issueA32(0); stageB(0, 0); writeA32(0); }   // writeA auto-waits A
    else       { stageA16(0, 0); stageB(0, 0); }

#pragma unroll
    for (int kt = 0; kt < 4; ++kt) {
        const int cb = kt & 1, nb = cb ^ 1;
        if (kt < 3) {                       // issue next tile (A first, then B)
            if (A_F32) issueA32(kt + 1); else stageA16(nb, kt + 1);
            stageB(nb, kt + 1);
        }
        // drain only tile-kt's loads; tile-(kt+1)'s stay in flight
        if (kt < 3) { if (A_F32) WAITV(12); else WAITV(8); }
        else        { WAITV(0); }
        SBAR();
        const _Float16* Ab = lds + cb * 16384;
        const _Float16* Bb = lds + 32768 + cb * 16384;
#pragma unroll
        for (int kk = 0; kk < 2; ++kk) {
            half8 af[8], bf[4];
#pragma unroll
            for (int mi = 0; mi < 8; ++mi) {
                const int R = wr + mi * 16 + l15;
                af[mi] = *(const half8*)(Ab + R * 64 + (((kk * 4 + lhi) ^ (R & 7)) * 8));
            }
#pragma unroll
            for (int nj = 0; nj < 4; ++nj) {
                const int R = wc + nj * 16 + l15;
                bf[nj] = *(const half8*)(Bb + R * 64 + (((kk * 4 + lhi) ^ (R & 7)) * 8));
            }
#pragma unroll
            for (int mi = 0; mi < 8; ++mi)
#pragma unroll
                for (int nj = 0; nj < 4; ++nj)
                    acc[mi][nj] = MFMA16(af[mi], bf[nj], acc[mi][nj]);
        }
        SBAR();
        if (A_F32 && kt < 3) writeA32(nb);   // ds_writes drained by next WAITV lgkmcnt(0)
    }

    // ---------------- epilogue ----------------
    const bool hi = DUAL && (y == 1);
    void* Cp = hi ? C1 : C0;
    const int cadj = hi ? 256 : 0;

    if (!OUT_F32) {
        // two half-tiles of 128 rows staged fp16 in LDS, stored as half8 rows
        _Float16* Cst = lds;   // [128][264]
#pragma unroll
        for (int h = 0; h < 2; ++h) {
            if ((wid >> 2) == h) {
#pragma unroll
                for (int mi = 0; mi < 8; ++mi) {
#pragma unroll
                    for (int nj = 0; nj < 4; ++nj) {
                        const int col = wc + nj * 16 + l15;
                        const float bv = ADD_BIAS ? bias[n0 + col - cadj] : 0.0f;
#pragma unroll
                        for (int j = 0; j < 4; ++j)
                            Cst[(mi * 16 + lhi * 4 + j) * 264 + col] =
                                (_Float16)(acc[mi][nj][j] + bv);
                    }
                }
            }
            __syncthreads();
            const int r  = tid >> 2;
            const int c0 = (tid & 3) * 64;
            const int grow = m0 + h * 128 + r;
            int orow;
            if (DUAL)             orow = hi ? grow : map_ln_nl(grow);
            else if (ROWMAP == 1) orow = map_ln_nl(grow);
            else if (ROWMAP == 2) orow = map_nl_ln(grow);
            else                  orow = grow;
            _Float16* dst = (_Float16*)Cp + (size_t)orow * 256 + (n0 - cadj) + c0;
            const _Float16* srcp = Cst + r * 264 + c0;
#pragma unroll
            for (int u = 0; u < 8; ++u)
                *(half8*)(dst + u * 8) = *(const half8*)(srcp + u * 8);
            __syncthreads();
        }
    } else {
        // fp32 output (final GEMM, ident rowmap): scalar path
#pragma unroll
        for (int mi = 0; mi < 8; ++mi) {
#pragma unroll
            for (int nj = 0; nj < 4; ++nj) {
                const int col = n0 + wc + nj * 16 + l15 - cadj;
                const float bv = ADD_BIAS ? bias[col] : 0.0f;
#pragma unroll
                for (int j = 0; j < 4; ++j) {
                    const int orow = m0 + wr + mi * 16 + lhi * 4 + j;
                    ((float*)Cp)[(size_t)orow * 256 + col] = acc[mi][nj][j] + bv;
                }
            }
        }
    }
}

// ---------------- temporal attention: per (b,n,h), seq = L = 128, NL layout ----------------
// Swapped QK^T: st = mfma(K_frag, Q_frag) -> lane holds S^T[k=rt*16+lhi*4+j][q=..+l15].
// Softmax reduce = in-lane + shfl_xor(16,32); P written as half4 (b64).
__global__ __launch_bounds__(256) void attn_temporal(
    const _Float16* __restrict__ Q, const _Float16* __restrict__ K,
    const _Float16* __restrict__ V, _Float16* __restrict__ O)
{
    __shared__ __align__(16) _Float16 Vt[32][136];   // V^T: [d][l]
    __shared__ __align__(16) _Float16 P[128][136];   // probabilities [q][k]

    const int tid  = threadIdx.x;
    const int lane = tid & 63;
    const int l15  = lane & 15;
    const int lhi  = lane >> 4;
    const int wid  = tid >> 6;
    const int bidx = blockIdx.x;
    const int h = bidx & 7;
    const int n = (bidx >> 3) & 63;
    const int b = bidx >> 9;
    const size_t base = ((size_t)(b * 64 + n) * 128) * 256 + (size_t)h * 32;

    // cooperative V transpose into LDS
    {
        const int l  = tid >> 1;
        const int dh = (tid & 1) * 16;
        const _Float16* srcp = V + base + (size_t)l * 256 + dh;
        half8 v0 = *(const half8*)(srcp);
        half8 v1 = *(const half8*)(srcp + 8);
#pragma unroll
        for (int j = 0; j < 8; ++j) {
            Vt[dh + j][l]     = v0[j];
            Vt[dh + 8 + j][l] = v1[j];
        }
    }
    __syncthreads();

    // S^T = K Q^T : wave owns q-cols [wid*32, wid*32+32), all 128 k-rows
    half8 qf[2];
#pragma unroll
    for (int ct = 0; ct < 2; ++ct)
        qf[ct] = *(const half8*)(Q + base +
                  (size_t)(wid * 32 + ct * 16 + l15) * 256 + lhi * 8);
    f32x4 st[2][8] = {};
#pragma unroll
    for (int rt = 0; rt < 8; ++rt) {
        half8 kf = *(const half8*)(K + base +
                    (size_t)(rt * 16 + l15) * 256 + lhi * 8);
#pragma unroll
        for (int ct = 0; ct < 2; ++ct)
            st[ct][rt] = MFMA16(kf, qf[ct], st[ct][rt]);
    }

    const float scale = 0.17677669529663687f;  // 1/sqrt(32)
#pragma unroll
    for (int ct = 0; ct < 2; ++ct) {
        const int q = wid * 32 + ct * 16 + l15;
        float m = st[ct][0][0];
#pragma unroll
        for (int rt = 0; rt < 8; ++rt)
#pragma unroll
            for (int j = 0; j < 4; ++j) m = fmaxf(m, st[ct][rt][j]);
        m = fmaxf(m, __shfl_xor(m, 16));
        m = fmaxf(m, __shfl_xor(m, 32));
        float sum = 0.0f;
#pragma unroll
        for (int rt = 0; rt < 8; ++rt)
#pragma unroll
            for (int j = 0; j < 4; ++j) {
                const float p = __expf((st[ct][rt][j] - m) * scale);
                st[ct][rt][j] = p;
                sum += p;
            }
        sum += __shfl_xor(sum, 16);
        sum += __shfl_xor(sum, 32);
        const float inv = 1.0f / sum;
#pragma unroll
        for (int rt = 0; rt < 8; ++rt) {
            half4 hv;
#pragma unroll
            for (int j = 0; j < 4; ++j) hv[j] = (_Float16)(st[ct][rt][j] * inv);
            *(half4*)(&P[q][rt * 16 + lhi * 4]) = hv;
        }
    }
    __syncthreads();

    // O = P V
    f32x4 o[2][2] = {};
#pragma unroll
    for (int ks = 0; ks < 4; ++ks) {
        half8 pa[2];
#pragma unroll
        for (int mi = 0; mi < 2; ++mi)
            pa[mi] = *(const half8*)(&P[wid * 32 + mi * 16 + l15][ks * 32 + lhi * 8]);
#pragma unroll
        for (int dt = 0; dt < 2; ++dt) {
            half8 vb = *(const half8*)(&Vt[dt * 16 + l15][ks * 32 + lhi * 8]);
#pragma unroll
            for (int mi = 0; mi < 2; ++mi)
                o[mi][dt] = MFMA16(pa[mi], vb, o[mi][dt]);
        }
    }
#pragma unroll
    for (int mi = 0; mi < 2; ++mi)
#pragma unroll
        for (int dt = 0; dt < 2; ++dt)
#pragma unroll
            for (int j = 0; j < 4; ++j)
                O[base + (size_t)(wid * 32 + mi * 16 + lhi * 4 + j) * 256 +
                  dt * 16 + l15] = (_Float16)o[mi][dt][j];
}

// ---------------- social attention: per (b,l,h), seq = N = 64, LN layout ----------------
__global__ __launch_bounds__(256) void attn_social(
    const _Float16* __restrict__ Q, const _Float16* __restrict__ K,
    const _Float16* __restrict__ V, _Float16* __restrict__ O)
{
    __shared__ __align__(16) _Float16 Vt[32][72];
    __shared__ __align__(16) _Float16 P[64][72];

    const int tid  = threadIdx.x;
    const int lane = tid & 63;
    const int l15  = lane & 15;
    const int lhi  = lane >> 4;
    const int wid  = tid >> 6;
    const int bidx = blockIdx.x;
    const int h = bidx & 7;
    const int l = (bidx >> 3) & 127;
    const int b = bidx >> 10;
    const size_t base = (((size_t)b * 128 + l) * 64) * 256 + (size_t)h * 32;

    {
        const int n  = tid >> 2;
        const int dq = (tid & 3) * 8;
        half8 v0 = *(const half8*)(V + base + (size_t)n * 256 + dq);
#pragma unroll
        for (int j = 0; j < 8; ++j) Vt[dq + j][n] = v0[j];
    }
    __syncthreads();

    // S^T : wave owns q-cols [wid*16, wid*16+16), all 64 k-rows
    half8 qf = *(const half8*)(Q + base + (size_t)(wid * 16 + l15) * 256 + lhi * 8);
    f32x4 st[4] = {};
#pragma unroll
    for (int rt = 0; rt < 4; ++rt) {
        half8 kf = *(const half8*)(K + base + (size_t)(rt * 16 + l15) * 256 + lhi * 8);
        st[rt] = MFMA16(kf, qf, st[rt]);
    }

    const float scale = 0.17677669529663687f;
    {
        const int q = wid * 16 + l15;
        float m = st[0][0];
#pragma unroll
        for (int rt = 0; rt < 4; ++rt)
#pragma unroll
            for (int j = 0; j < 4; ++j) m = fmaxf(m, st[rt][j]);
        m = fmaxf(m, __shfl_xor(m, 16));
        m = fmaxf(m, __shfl_xor(m, 32));
        float sum = 0.0f;
#pragma unroll
        for (int rt = 0; rt < 4; ++rt)
#pragma unroll
            for (int j = 0; j < 4; ++j) {
                const float p = __expf((st[rt][j] - m) * scale);
                st[rt][j] = p;
                sum += p;
            }
        sum += __shfl_xor(sum, 16);
        sum += __shfl_xor(sum, 32);
        const float inv = 1.0f / sum;
#pragma unroll
        for (int rt = 0; rt < 4; ++rt) {
            half4 hv;
#pragma unroll
            for (int j = 0; j < 4; ++j) hv[j] = (_Float16)(st[rt][j] * inv);
            *(half4*)(&P[q][rt * 16 + lhi * 4]) = hv;
        }
    }
    __syncthreads();

    f32x4 o[2] = {};
#pragma unroll
    for (int ks = 0; ks < 2; ++ks) {
        half8 pa = *(const half8*)(&P[wid * 16 + l15][ks * 32 + lhi * 8]);
#pragma unroll
        for (int dt = 0; dt < 2; ++dt) {
            half8 vb = *(const half8*)(&Vt[dt * 16 + l15][ks * 32 + lhi * 8]);
            o[dt] = MFMA16(pa, vb, o[dt]);
        }
    }
#pragma unroll
    for (int dt = 0; dt < 2; ++dt)
#pragma unroll
        for (int j = 0; j < 4; ++j)
            O[base + (size_t)(wid * 16 + lhi * 4 + j) * 256 + dt * 16 + l15] =
                (_Float16)o[dt][j];
}

// ---------------- host launch ----------------
extern "C" void kernel_launch(void* const* d_in, const int* in_sizes, int n_in,
                              void* d_out, int out_size, void* d_ws, size_t ws_size,
                              hipStream_t stream)
{
    const float* q    = (const float*)d_in[0];
    const float* k    = (const float*)d_in[1];
    const float* v    = (const float*)d_in[2];
    const float* t_wq = (const float*)d_in[3];
    const float* t_wk = (const float*)d_in[4];
    const float* t_wv = (const float*)d_in[5];
    const float* t_wd = (const float*)d_in[6];
    const float* t_bd = (const float*)d_in[7];
    const float* s_wq = (const float*)d_in[8];
    const float* s_wk = (const float*)d_in[9];
    const float* s_wv = (const float*)d_in[10];
    const float* s_wd = (const float*)d_in[11];
    const float* s_bd = (const float*)d_in[12];

    // workspace: 7 fp16 weight slots + b2 (fp32) + 6 activation slots (32 MB)
    _Float16* Wb = (_Float16*)d_ws;
    float* b2 = (float*)(Wb + 7 * 65536);
    const size_t SLOT = (size_t)65536 * 256;
    _Float16* S0 = (_Float16*)(b2 + 256);
    _Float16* S1 = S0 + SLOT;
    _Float16* S2 = S0 + 2 * SLOT;
    _Float16* S3 = S0 + 3 * SLOT;
    _Float16* S4 = S0 + 4 * SLOT;
    _Float16* S5 = S0 + 5 * SLOT;

    cvt_weights<<<dim3(256, 6), 256, 0, stream>>>(
        t_wq, t_wk, s_wk, t_wv, s_wv, s_wd, Wb);
    make_w2<<<256, 256, 0, stream>>>(s_wq, t_wd, t_bd, Wb + 5 * 65536, b2);

    const dim3 gb2(512);
    // Qt(NL) = q @ t_wq^T -> S1   (fp32 A read directly)
    gemm16<true, 1, false, false, false><<<256, gb2, 0, stream>>>(
        q, Wb + 0 * 65536, nullptr, S1, nullptr);
    // Kt(NL) -> S2, Ks(LN) -> S3  (dual over [t_wk; s_wk])
    gemm16<true, 1, true, false, false><<<512, gb2, 0, stream>>>(
        k, Wb + 1 * 65536, nullptr, S2, S3);
    // Vt(NL) -> S4, Vs(LN) -> S5
    gemm16<true, 1, true, false, false><<<512, gb2, 0, stream>>>(
        v, Wb + 3 * 65536, nullptr, S4, S5);

    attn_temporal<<<4096, 256, 0, stream>>>(S1, S2, S4, S0);   // Ot(NL) -> S0

    // Qs(LN) = Ot @ W2^T + b2 -> S1
    gemm16<false, 2, false, true, false><<<256, gb2, 0, stream>>>(
        S0, Wb + 5 * 65536, b2, S1, nullptr);

    attn_social<<<8192, 256, 0, stream>>>(S1, S3, S5, S2);     // Os(LN) -> S2

    gemm16<false, 0, false, true, true><<<256, gb2, 0, stream>>>(
        S2, Wb + 6 * 65536, s_bd, d_out, nullptr);

    (void)in_sizes; (void)n_in; (void)out_size; (void)ws_size;
}

// Round 8
// 277.730 us; speedup vs baseline: 1.5177x; 1.0413x over previous
//
#include <hip/hip_runtime.h>

typedef __attribute__((ext_vector_type(8))) _Float16 half8;
typedef __attribute__((ext_vector_type(4))) _Float16 half4;
typedef __attribute__((ext_vector_type(4))) float f32x4;

#define MFMA16(a, b, c) __builtin_amdgcn_mfma_f32_16x16x32_f16((a), (b), (c), 0, 0, 0)

// counted waitcnt + raw barrier (asm, memory-clobbered: no mem op crosses)
#define WAITV(N) asm volatile("s_waitcnt vmcnt(" #N ") lgkmcnt(0)" ::: "memory")
#define SBAR()   asm volatile("s_barrier" ::: "memory")

// B=8, L=128, N=64, D=256, H=8, dk=32.  M = 65536 tokens.
// Token orders: LN = (b,l,n), NL = (b,n,l).

__device__ inline int map_ln_nl(int t) {   // (b,l,n) -> (b,n,l)
    return (t & ~8191) | ((t & 63) << 7) | ((t >> 6) & 127);
}

typedef const __attribute__((address_space(1))) unsigned int guint;
typedef __attribute__((address_space(3))) unsigned int luint;
__device__ inline void gld16(const _Float16* g, _Float16* l) {
    __builtin_amdgcn_global_load_lds((guint*)g, (luint*)l, 16, 0, 0);
}

// ---------------- weight fp32 -> fp16 ----------------
// slots: 0=t_wq 1=t_wk 2=s_wk 3=t_wv 4=s_wv 5=W2(made elsewhere) 6=s_wd
__global__ __launch_bounds__(256) void cvt_weights(
    const float* __restrict__ w0, const float* __restrict__ w1,
    const float* __restrict__ w2, const float* __restrict__ w3,
    const float* __restrict__ w4, const float* __restrict__ w5,
    _Float16* __restrict__ out)
{
    const float* src[6] = {w0, w1, w2, w3, w4, w5};
    const int m = blockIdx.y;
    const int slot = (m < 5) ? m : 6;
    const int i = blockIdx.x * 256 + threadIdx.x;
    out[(size_t)slot * 65536 + i] = (_Float16)src[m][i];
}

// ---------------- W2 = s_wq @ t_wd (fp32 accum), b2 = s_wq @ t_bd ----------------
__global__ __launch_bounds__(256) void make_w2(
    const float* __restrict__ s_wq, const float* __restrict__ t_wd,
    const float* __restrict__ t_bd, _Float16* __restrict__ W2,
    float* __restrict__ b2)
{
    const int e = blockIdx.x;
    const int d = threadIdx.x;
    float acc = 0.0f;
    for (int c = 0; c < 256; ++c)
        acc = fmaf(s_wq[e * 256 + c], t_wd[c * 256 + d], acc);
    W2[e * 256 + d] = (_Float16)acc;
    if (d == 0) {
        float bb = 0.0f;
        for (int c = 0; c < 256; ++c) bb = fmaf(s_wq[e * 256 + c], t_bd[c], bb);
        b2[e] = bb;
    }
}

// ---------------- GEMM: C[M,*] = A[M,256] @ W[*,256]^T ----------------
// R7 structure (best measured): 256x256 tile, BK=64, 8 waves, counted vmcnt.
template <bool A_F32, int ROWMAP, bool DUAL, bool ADD_BIAS, bool OUT_F32>
__global__ __launch_bounds__(512, 2) void gemm16(
    const void* __restrict__ Ap, const _Float16* __restrict__ W,
    const float* __restrict__ bias, void* __restrict__ C0, void* __restrict__ C1)
{
    __shared__ __align__(16) _Float16 lds[65536];   // 128 KB

    const int tid  = threadIdx.x;
    const int lane = tid & 63;
    const int l15  = lane & 15;
    const int lhi  = lane >> 4;
    const int wid  = tid >> 6;
    const int nwg  = gridDim.x;
    const int wg   = (blockIdx.x & 7) * (nwg >> 3) + (blockIdx.x >> 3);
    const int y    = DUAL ? (wg & 1) : 0;
    const int x    = DUAL ? (wg >> 1) : wg;
    const int m0   = x * 256;
    const int n0   = y * 256;
    const int wr   = (wid >> 2) * 128;
    const int wc   = (wid & 3) * 64;

    int rr[4], cc[4];
#pragma unroll
    for (int i = 0; i < 4; ++i) {
        const int c = i * 512 + tid;
        const int r = c >> 3;
        rr[i] = r;
        cc[i] = ((c & 7) ^ (r & 7)) * 8;   // pre-swizzled column
    }

    f32x4 arA[4][2];

    auto issueA32 = [&](int kt) {
        const float* A = (const float*)Ap;
        const int k0 = kt * 64;
#pragma unroll
        for (int i = 0; i < 4; ++i) {
            const float* p = A + (size_t)(m0 + rr[i]) * 256 + k0 + cc[i];
            arA[i][0] = *(const f32x4*)(p);
            arA[i][1] = *(const f32x4*)(p + 4);
        }
    };
    auto writeA32 = [&](int buf) {
        _Float16* Ad = lds + buf * 16384;
#pragma unroll
        for (int i = 0; i < 4; ++i) {
            half8 h;
#pragma unroll
            for (int q = 0; q < 4; ++q) {
                h[q]     = (_Float16)arA[i][0][q];
                h[4 + q] = (_Float16)arA[i][1][q];
            }
            *(half8*)(Ad + (i * 512 + tid) * 8) = h;
        }
    };
    auto stageA16 = [&](int buf, int kt) {
        const _Float16* A = (const _Float16*)Ap;
        _Float16* Ad = lds + buf * 16384;
        const int k0 = kt * 64;
#pragma unroll
        for (int i = 0; i < 4; ++i)
            gld16(A + (size_t)(m0 + rr[i]) * 256 + k0 + cc[i],
                  Ad + (i * 512 + tid) * 8);
    };
    auto stageB = [&](int buf, int kt) {
        _Float16* Bd = lds + 32768 + buf * 16384;
        const int k0 = kt * 64;
#pragma unroll
        for (int i = 0; i < 4; ++i)
            gld16(W + (size_t)(n0 + rr[i]) * 256 + k0 + cc[i],
                  Bd + (i * 512 + tid) * 8);
    };

    f32x4 acc[8][4] = {};

    if (A_F32) { issueA32(0); stageB(0, 0); writeA32(0); }
    else       { stageA16(0, 0); stageB(0, 0); }

#pragma unroll
    for (int kt = 0; kt < 4; ++kt) {
        const int cb = kt & 1, nb = cb ^ 1;
        if (kt < 3) {
            if (A_F32) issueA32(kt + 1); else stageA16(nb, kt + 1);
            stageB(nb, kt + 1);
        }
        if (kt < 3) { if (A_F32) WAITV(12); else WAITV(8); }
        else        { WAITV(0); }
        SBAR();
        const _Float16* Ab = lds + cb * 16384;
        const _Float16* Bb = lds + 32768 + cb * 16384;
#pragma unroll
        for (int kk = 0; kk < 2; ++kk) {
            half8 af[8], bf[4];
#pragma unroll
            for (int mi = 0; mi < 8; ++mi) {
                const int R = wr + mi * 16 + l15;
                af[mi] = *(const half8*)(Ab + R * 64 + (((kk * 4 + lhi) ^ (R & 7)) * 8));
            }
#pragma unroll
            for (int nj = 0; nj < 4; ++nj) {
                const int R = wc + nj * 16 + l15;
                bf[nj] = *(const half8*)(Bb + R * 64 + (((kk * 4 + lhi) ^ (R & 7)) * 8));
            }
#pragma unroll
            for (int mi = 0; mi < 8; ++mi)
#pragma unroll
                for (int nj = 0; nj < 4; ++nj)
                    acc[mi][nj] = MFMA16(af[mi], bf[nj], acc[mi][nj]);
        }
        SBAR();
        if (A_F32 && kt < 3) writeA32(nb);
    }

    // ---------------- epilogue ----------------
    const bool hi = DUAL && (y == 1);
    void* Cp = hi ? C1 : C0;
    const int cadj = hi ? 256 : 0;

    _Float16* Cst = lds;   // [128][264]
#pragma unroll
    for (int h = 0; h < 2; ++h) {
        if ((wid >> 2) == h) {
#pragma unroll
            for (int mi = 0; mi < 8; ++mi) {
#pragma unroll
                for (int nj = 0; nj < 4; ++nj) {
                    const int col = wc + nj * 16 + l15;
                    const float bv = ADD_BIAS ? bias[n0 + col - cadj] : 0.0f;
#pragma unroll
                    for (int j = 0; j < 4; ++j)
                        Cst[(mi * 16 + lhi * 4 + j) * 264 + col] =
                            (_Float16)(acc[mi][nj][j] + bv);
                }
            }
        }
        __syncthreads();
        const int r  = tid >> 2;
        const int c0 = (tid & 3) * 64;
        const int grow = m0 + h * 128 + r;
        int orow;
        if (DUAL)             orow = hi ? grow : map_ln_nl(grow);
        else if (ROWMAP == 1) orow = map_ln_nl(grow);
        else                  orow = grow;
        _Float16* dst = (_Float16*)Cp + (size_t)orow * 256 + (n0 - cadj) + c0;
        const _Float16* srcp = Cst + r * 264 + c0;
#pragma unroll
        for (int u = 0; u < 8; ++u)
            *(half8*)(dst + u * 8) = *(const half8*)(srcp + u * 8);
        __syncthreads();
    }
}

// ---------------- temporal attention: per (b,n,h), seq = L = 128, NL layout ----------------
__global__ __launch_bounds__(256) void attn_temporal(
    const _Float16* __restrict__ Q, const _Float16* __restrict__ K,
    const _Float16* __restrict__ V, _Float16* __restrict__ O)
{
    __shared__ __align__(16) _Float16 Vt[32][136];   // V^T: [d][l]
    __shared__ __align__(16) _Float16 P[128][136];   // probabilities [q][k]

    const int tid  = threadIdx.x;
    const int lane = tid & 63;
    const int l15  = lane & 15;
    const int lhi  = lane >> 4;
    const int wid  = tid >> 6;
    const int bidx = blockIdx.x;
    const int h = bidx & 7;
    const int n = (bidx >> 3) & 63;
    const int b = bidx >> 9;
    const size_t base = ((size_t)(b * 64 + n) * 128) * 256 + (size_t)h * 32;

    {
        const int l  = tid >> 1;
        const int dh = (tid & 1) * 16;
        const _Float16* srcp = V + base + (size_t)l * 256 + dh;
        half8 v0 = *(const half8*)(srcp);
        half8 v1 = *(const half8*)(srcp + 8);
#pragma unroll
        for (int j = 0; j < 8; ++j) {
            Vt[dh + j][l]     = v0[j];
            Vt[dh + 8 + j][l] = v1[j];
        }
    }
    __syncthreads();

    half8 qf[2];
#pragma unroll
    for (int ct = 0; ct < 2; ++ct)
        qf[ct] = *(const half8*)(Q + base +
                  (size_t)(wid * 32 + ct * 16 + l15) * 256 + lhi * 8);
    f32x4 st[2][8] = {};
#pragma unroll
    for (int rt = 0; rt < 8; ++rt) {
        half8 kf = *(const half8*)(K + base +
                    (size_t)(rt * 16 + l15) * 256 + lhi * 8);
#pragma unroll
        for (int ct = 0; ct < 2; ++ct)
            st[ct][rt] = MFMA16(kf, qf[ct], st[ct][rt]);
    }

    const float scale = 0.17677669529663687f;  // 1/sqrt(32)
#pragma unroll
    for (int ct = 0; ct < 2; ++ct) {
        const int q = wid * 32 + ct * 16 + l15;
        float m = st[ct][0][0];
#pragma unroll
        for (int rt = 0; rt < 8; ++rt)
#pragma unroll
            for (int j = 0; j < 4; ++j) m = fmaxf(m, st[ct][rt][j]);
        m = fmaxf(m, __shfl_xor(m, 16));
        m = fmaxf(m, __shfl_xor(m, 32));
        float sum = 0.0f;
#pragma unroll
        for (int rt = 0; rt < 8; ++rt)
#pragma unroll
            for (int j = 0; j < 4; ++j) {
                const float p = __expf((st[ct][rt][j] - m) * scale);
                st[ct][rt][j] = p;
                sum += p;
            }
        sum += __shfl_xor(sum, 16);
        sum += __shfl_xor(sum, 32);
        const float inv = 1.0f / sum;
#pragma unroll
        for (int rt = 0; rt < 8; ++rt) {
            half4 hv;
#pragma unroll
            for (int j = 0; j < 4; ++j) hv[j] = (_Float16)(st[ct][rt][j] * inv);
            *(half4*)(&P[q][rt * 16 + lhi * 4]) = hv;
        }
    }
    __syncthreads();

    f32x4 o[2][2] = {};
#pragma unroll
    for (int ks = 0; ks < 4; ++ks) {
        half8 pa[2];
#pragma unroll
        for (int mi = 0; mi < 2; ++mi)
            pa[mi] = *(const half8*)(&P[wid * 32 + mi * 16 + l15][ks * 32 + lhi * 8]);
#pragma unroll
        for (int dt = 0; dt < 2; ++dt) {
            half8 vb = *(const half8*)(&Vt[dt * 16 + l15][ks * 32 + lhi * 8]);
#pragma unroll
            for (int mi = 0; mi < 2; ++mi)
                o[mi][dt] = MFMA16(pa[mi], vb, o[mi][dt]);
        }
    }
#pragma unroll
    for (int mi = 0; mi < 2; ++mi)
#pragma unroll
        for (int dt = 0; dt < 2; ++dt)
#pragma unroll
            for (int j = 0; j < 4; ++j)
                O[base + (size_t)(wid * 32 + mi * 16 + lhi * 4 + j) * 256 +
                  dt * 16 + l15] = (_Float16)o[mi][dt][j];
}

// ---------------- fused social stage: per (b,l), 8 waves = 8 heads ----------------
// Qs = Ot@W2^T + b2 (in-block), attention over N=64, out = O@s_wd^T + s_bd (fp32).
// LDS regions (halfs): R_AD [0,18432): Ot[64][264] -> V^T 8x[32][72] -> outF(f32, w/ R_B)
//                      R_B [18432,38912): Qs 8x[64][40]
//                      R_C [38912,75776): P 8x[64][72] -> O[64][264]
__global__ __launch_bounds__(512) void attn_social_fused(
    const _Float16* __restrict__ Ot,   // NL (b,n,l,d) fp16
    const _Float16* __restrict__ Ks,   // LN fp16
    const _Float16* __restrict__ Vs,   // LN fp16
    const _Float16* __restrict__ W2,   // fp16 [256][256]
    const float*    __restrict__ b2,   // fp32 [256]
    const _Float16* __restrict__ Wd,   // s_wd fp16 [256][256]
    const float*    __restrict__ bd,   // s_bd fp32 [256]
    float* __restrict__ out)           // LN fp32
{
    __shared__ __align__(16) _Float16 lds[75776];   // 148 KB

    const int tid  = threadIdx.x;
    const int lane = tid & 63;
    const int l15  = lane & 15;
    const int lhi  = lane >> 4;
    const int h    = tid >> 6;          // wave = head
    const int l = blockIdx.x & 127;
    const int b = blockIdx.x >> 7;

    _Float16* Ot_lds = lds;                        // [64][264]
    _Float16* Vt_h   = lds + h * 2304;             // [32][72] (after BAR2)
    _Float16* Qs_h   = lds + 18432 + h * 2560;     // [64][40]
    _Float16* P_h    = lds + 38912 + h * 4608;     // [64][72]
    _Float16* O_lds  = lds + 38912;                // [64][264] (after BAR3)
    float*    outF   = (float*)lds;                // [64][260] (after BAR4)

    const size_t kvbase = ((size_t)(b * 128 + l) * 64) * 256;

    // ---- phase 1: stage Ot slice: tokens (b, n, l), n = 0..63 ----
#pragma unroll
    for (int i = 0; i < 4; ++i) {
        const int chunk = i * 512 + tid;           // 2048 chunks of 8 halfs
        const int r  = chunk >> 5;
        const int c8 = (chunk & 31) * 8;
        half8 v = *(const half8*)(Ot + ((size_t)(b * 64 + r) * 128 + l) * 256 + c8);
        *(half8*)(Ot_lds + r * 264 + c8) = v;
    }
    __syncthreads();                               // BAR1

    // ---- phase 2: Qs_h = Ot @ W2_h^T + b2_h  (D: row=d', col=token) ----
    {
        float b2v[2][4];
#pragma unroll
        for (int mt = 0; mt < 2; ++mt)
#pragma unroll
            for (int j = 0; j < 4; ++j)
                b2v[mt][j] = b2[h * 32 + mt * 16 + lhi * 4 + j];

        f32x4 qacc[2][4] = {};
#pragma unroll
        for (int ks = 0; ks < 8; ++ks) {
            half8 wf[2], of[4];
#pragma unroll
            for (int mt = 0; mt < 2; ++mt)
                wf[mt] = *(const half8*)(W2 + (size_t)(h * 32 + mt * 16 + l15) * 256 + ks * 32 + lhi * 8);
#pragma unroll
            for (int tg = 0; tg < 4; ++tg)
                of[tg] = *(const half8*)(Ot_lds + (tg * 16 + l15) * 264 + ks * 32 + lhi * 8);
#pragma unroll
            for (int mt = 0; mt < 2; ++mt)
#pragma unroll
                for (int tg = 0; tg < 4; ++tg)
                    qacc[mt][tg] = MFMA16(wf[mt], of[tg], qacc[mt][tg]);
        }
#pragma unroll
        for (int mt = 0; mt < 2; ++mt)
#pragma unroll
            for (int tg = 0; tg < 4; ++tg) {
                half4 hv;
#pragma unroll
                for (int j = 0; j < 4; ++j)
                    hv[j] = (_Float16)(qacc[mt][tg][j] + b2v[mt][j]);
                *(half4*)(Qs_h + (tg * 16 + l15) * 40 + mt * 16 + lhi * 4) = hv;
            }
    }
    __syncthreads();                               // BAR2 (Ot region freed)

    // ---- phase 3a: stage V^T for this head into freed region ----
    {
        half8 vv[4];
#pragma unroll
        for (int i = 0; i < 4; ++i)
            vv[i] = *(const half8*)(Vs + kvbase + (size_t)lane * 256 + h * 32 + i * 8);
#pragma unroll
        for (int i = 0; i < 4; ++i)
#pragma unroll
            for (int j = 0; j < 8; ++j)
                Vt_h[(i * 8 + j) * 72 + lane] = vv[i][j];
    }

    // ---- phase 3b: S^T = Ks_h . Qs_h (swapped: lane holds k-rows for q-col l15) ----
    half8 qf[4];
#pragma unroll
    for (int g = 0; g < 4; ++g)
        qf[g] = *(const half8*)(Qs_h + (g * 16 + l15) * 40 + lhi * 8);
    f32x4 st[4][4] = {};
#pragma unroll
    for (int rt = 0; rt < 4; ++rt) {
        half8 kf = *(const half8*)(Ks + kvbase + (size_t)(rt * 16 + l15) * 256 + h * 32 + lhi * 8);
#pragma unroll
        for (int g = 0; g < 4; ++g)
            st[g][rt] = MFMA16(kf, qf[g], st[g][rt]);
    }

    // ---- phase 3c: softmax per q-col, write P ----
    const float scale = 0.17677669529663687f;
#pragma unroll
    for (int g = 0; g < 4; ++g) {
        const int q = g * 16 + l15;
        float m = st[g][0][0];
#pragma unroll
        for (int rt = 0; rt < 4; ++rt)
#pragma unroll
            for (int j = 0; j < 4; ++j) m = fmaxf(m, st[g][rt][j]);
        m = fmaxf(m, __shfl_xor(m, 16));
        m = fmaxf(m, __shfl_xor(m, 32));
        float sum = 0.0f;
#pragma unroll
        for (int rt = 0; rt < 4; ++rt)
#pragma unroll
            for (int j = 0; j < 4; ++j) {
                const float p = __expf((st[g][rt][j] - m) * scale);
                st[g][rt][j] = p;
                sum += p;
            }
        sum += __shfl_xor(sum, 16);
        sum += __shfl_xor(sum, 32);
        const float inv = 1.0f / sum;
#pragma unroll
        for (int rt = 0; rt < 4; ++rt) {
            half4 hv;
#pragma unroll
            for (int j = 0; j < 4; ++j) hv[j] = (_Float16)(st[g][rt][j] * inv);
            *(half4*)(P_h + q * 72 + rt * 16 + lhi * 4) = hv;
        }
    }

    // ---- phase 3d: O_h = P V  (per-wave private LDS) ----
    f32x4 o[4][2] = {};
#pragma unroll
    for (int ks = 0; ks < 2; ++ks) {
        half8 vb[2];
#pragma unroll
        for (int dt = 0; dt < 2; ++dt)
            vb[dt] = *(const half8*)(Vt_h + (dt * 16 + l15) * 72 + ks * 32 + lhi * 8);
#pragma unroll
        for (int g = 0; g < 4; ++g) {
            half8 pa = *(const half8*)(P_h + (g * 16 + l15) * 72 + ks * 32 + lhi * 8);
#pragma unroll
            for (int dt = 0; dt < 2; ++dt)
                o[g][dt] = MFMA16(pa, vb[dt], o[g][dt]);
        }
    }
    __syncthreads();                               // BAR3 (P/V^T regions freed)

    // ---- phase 4: O -> LDS [token][d], heads side by side ----
#pragma unroll
    for (int g = 0; g < 4; ++g)
#pragma unroll
        for (int dt = 0; dt < 2; ++dt)
#pragma unroll
            for (int j = 0; j < 4; ++j)
                O_lds[(g * 16 + lhi * 4 + j) * 264 + h * 32 + dt * 16 + l15] =
                    (_Float16)o[g][dt][j];
    __syncthreads();                               // BAR4

    // ---- phase 5: out = O @ s_wd^T + bd; wave h -> out-cols [h*32, h*32+32) ----
    {
        f32x4 oc[4][2] = {};
#pragma unroll
        for (int ks = 0; ks < 8; ++ks) {
            half8 af[4], wf2[2];
#pragma unroll
            for (int g2 = 0; g2 < 4; ++g2)
                af[g2] = *(const half8*)(O_lds + (g2 * 16 + l15) * 264 + ks * 32 + lhi * 8);
#pragma unroll
            for (int nt = 0; nt < 2; ++nt)
                wf2[nt] = *(const half8*)(Wd + (size_t)(h * 32 + nt * 16 + l15) * 256 + ks * 32 + lhi * 8);
#pragma unroll
            for (int g2 = 0; g2 < 4; ++g2)
#pragma unroll
                for (int nt = 0; nt < 2; ++nt)
                    oc[g2][nt] = MFMA16(af[g2], wf2[nt], oc[g2][nt]);
        }
        float bdv[2] = { bd[h * 32 + l15], bd[h * 32 + 16 + l15] };
        // outF overlaps Qs/V^T regions (dead since BAR4); NOT O_lds.
#pragma unroll
        for (int g2 = 0; g2 < 4; ++g2)
#pragma unroll
            for (int nt = 0; nt < 2; ++nt)
#pragma unroll
                for (int j = 0; j < 4; ++j)
                    outF[(g2 * 16 + lhi * 4 + j) * 260 + h * 32 + nt * 16 + l15] =
                        oc[g2][nt][j] + bdv[nt];
    }
    __syncthreads();                               // BAR5

    // ---- phase 6: coalesced fp32 store ----
#pragma unroll
    for (int i = 0; i < 8; ++i) {
        const int slot = i * 512 + tid;            // 4096 f32x4
        const int r  = slot >> 6;
        const int c4 = (slot & 63) * 4;
        f32x4 v = *(const f32x4*)(outF + r * 260 + c4);
        *(f32x4*)(out + ((size_t)(b * 128 + l) * 64 + r) * 256 + c4) = v;
    }
}

// ---------------- host launch ----------------
extern "C" void kernel_launch(void* const* d_in, const int* in_sizes, int n_in,
                              void* d_out, int out_size, void* d_ws, size_t ws_size,
                              hipStream_t stream)
{
    const float* q    = (const float*)d_in[0];
    const float* k    = (const float*)d_in[1];
    const float* v    = (const float*)d_in[2];
    const float* t_wq = (const float*)d_in[3];
    const float* t_wk = (const float*)d_in[4];
    const float* t_wv = (const float*)d_in[5];
    const float* t_wd = (const float*)d_in[6];
    const float* t_bd = (const float*)d_in[7];
    const float* s_wq = (const float*)d_in[8];
    const float* s_wk = (const float*)d_in[9];
    const float* s_wv = (const float*)d_in[10];
    const float* s_wd = (const float*)d_in[11];
    const float* s_bd = (const float*)d_in[12];

    // workspace: 7 fp16 weight slots + b2 (fp32) + 6 activation slots (32 MB)
    _Float16* Wb = (_Float16*)d_ws;
    float* b2 = (float*)(Wb + 7 * 65536);
    const size_t SLOT = (size_t)65536 * 256;
    _Float16* S0 = (_Float16*)(b2 + 256);
    _Float16* S1 = S0 + SLOT;
    _Float16* S2 = S0 + 2 * SLOT;
    _Float16* S3 = S0 + 3 * SLOT;
    _Float16* S4 = S0 + 4 * SLOT;
    _Float16* S5 = S0 + 5 * SLOT;

    cvt_weights<<<dim3(256, 6), 256, 0, stream>>>(
        t_wq, t_wk, s_wk, t_wv, s_wv, s_wd, Wb);
    make_w2<<<256, 256, 0, stream>>>(s_wq, t_wd, t_bd, Wb + 5 * 65536, b2);

    // Qt(NL) = q @ t_wq^T -> S1   (fp32 A read directly)
    gemm16<true, 1, false, false, false><<<256, 512, 0, stream>>>(
        q, Wb + 0 * 65536, nullptr, S1, nullptr);
    // Kt(NL) -> S2, Ks(LN) -> S3  (dual over [t_wk; s_wk])
    gemm16<true, 1, true, false, false><<<512, 512, 0, stream>>>(
        k, Wb + 1 * 65536, nullptr, S2, S3);
    // Vt(NL) -> S4, Vs(LN) -> S5
    gemm16<true, 1, true, false, false><<<512, 512, 0, stream>>>(
        v, Wb + 3 * 65536, nullptr, S4, S5);

    attn_temporal<<<4096, 256, 0, stream>>>(S1, S2, S4, S0);   // Ot(NL) -> S0

    // fused: Qs-proj + social attention + out-proj
    attn_social_fused<<<1024, 512, 0, stream>>>(
        S0, S3, S5, Wb + 5 * 65536, b2, Wb + 6 * 65536, s_bd, (float*)d_out);

    (void)in_sizes; (void)n_in; (void)out_size; (void)ws_size;
}

// Round 9
// 262.336 us; speedup vs baseline: 1.6068x; 1.0587x over previous
//
#include <hip/hip_runtime.h>

typedef __attribute__((ext_vector_type(8))) _Float16 half8;
typedef __attribute__((ext_vector_type(4))) _Float16 half4;
typedef __attribute__((ext_vector_type(4))) float f32x4;

#define MFMA16(a, b, c) __builtin_amdgcn_mfma_f32_16x16x32_f16((a), (b), (c), 0, 0, 0)
#define MFMA16K16(a, b, c) __builtin_amdgcn_mfma_f32_16x16x16f16((a), (b), (c), 0, 0, 0)

// counted waitcnt + raw barrier (asm, memory-clobbered: no mem op crosses)
#define WAITV(N) asm volatile("s_waitcnt vmcnt(" #N ") lgkmcnt(0)" ::: "memory")
#define SBAR()   asm volatile("s_barrier" ::: "memory")

// B=8, L=128, N=64, D=256, H=8, dk=32.  M = 65536 tokens.
// Token orders: LN = (b,l,n), NL = (b,n,l).

__device__ inline int map_ln_nl(int t) {   // (b,l,n) -> (b,n,l)
    return (t & ~8191) | ((t & 63) << 7) | ((t >> 6) & 127);
}

typedef const __attribute__((address_space(1))) unsigned int guint;
typedef __attribute__((address_space(3))) unsigned int luint;
__device__ inline void gld16(const _Float16* g, _Float16* l) {
    __builtin_amdgcn_global_load_lds((guint*)g, (luint*)l, 16, 0, 0);
}

// ---------------- weight fp32 -> fp16 ----------------
// slots: 0=t_wq 1=t_wk 2=s_wk 3=t_wv 4=s_wv 5=W2(made elsewhere) 6=s_wd
__global__ __launch_bounds__(256) void cvt_weights(
    const float* __restrict__ w0, const float* __restrict__ w1,
    const float* __restrict__ w2, const float* __restrict__ w3,
    const float* __restrict__ w4, const float* __restrict__ w5,
    _Float16* __restrict__ out)
{
    const float* src[6] = {w0, w1, w2, w3, w4, w5};
    const int m = blockIdx.y;
    const int slot = (m < 5) ? m : 6;
    const int i = blockIdx.x * 256 + threadIdx.x;
    out[(size_t)slot * 65536 + i] = (_Float16)src[m][i];
}

// ---------------- W2 = s_wq @ t_wd (fp32 accum), b2 = s_wq @ t_bd ----------------
__global__ __launch_bounds__(256) void make_w2(
    const float* __restrict__ s_wq, const float* __restrict__ t_wd,
    const float* __restrict__ t_bd, _Float16* __restrict__ W2,
    float* __restrict__ b2)
{
    const int e = blockIdx.x;
    const int d = threadIdx.x;
    float acc = 0.0f;
    for (int c = 0; c < 256; ++c)
        acc = fmaf(s_wq[e * 256 + c], t_wd[c * 256 + d], acc);
    W2[e * 256 + d] = (_Float16)acc;
    if (d == 0) {
        float bb = 0.0f;
        for (int c = 0; c < 256; ++c) bb = fmaf(s_wq[e * 256 + c], t_bd[c], bb);
        b2[e] = bb;
    }
}

// ---------------- GEMM: C[M,*] = A[M,256] @ W[*,256]^T ----------------
// R7 structure: 256x256 tile, BK=64, 8 waves, counted vmcnt.
template <bool A_F32, int ROWMAP, bool DUAL, bool ADD_BIAS, bool OUT_F32>
__global__ __launch_bounds__(512, 2) void gemm16(
    const void* __restrict__ Ap, const _Float16* __restrict__ W,
    const float* __restrict__ bias, void* __restrict__ C0, void* __restrict__ C1)
{
    __shared__ __align__(16) _Float16 lds[65536];   // 128 KB

    const int tid  = threadIdx.x;
    const int lane = tid & 63;
    const int l15  = lane & 15;
    const int lhi  = lane >> 4;
    const int wid  = tid >> 6;
    const int nwg  = gridDim.x;
    const int wg   = (blockIdx.x & 7) * (nwg >> 3) + (blockIdx.x >> 3);
    const int y    = DUAL ? (wg & 1) : 0;
    const int x    = DUAL ? (wg >> 1) : wg;
    const int m0   = x * 256;
    const int n0   = y * 256;
    const int wr   = (wid >> 2) * 128;
    const int wc   = (wid & 3) * 64;

    int rr[4], cc[4];
#pragma unroll
    for (int i = 0; i < 4; ++i) {
        const int c = i * 512 + tid;
        const int r = c >> 3;
        rr[i] = r;
        cc[i] = ((c & 7) ^ (r & 7)) * 8;   // pre-swizzled column
    }

    f32x4 arA[4][2];

    auto issueA32 = [&](int kt) {
        const float* A = (const float*)Ap;
        const int k0 = kt * 64;
#pragma unroll
        for (int i = 0; i < 4; ++i) {
            const float* p = A + (size_t)(m0 + rr[i]) * 256 + k0 + cc[i];
            arA[i][0] = *(const f32x4*)(p);
            arA[i][1] = *(const f32x4*)(p + 4);
        }
    };
    auto writeA32 = [&](int buf) {
        _Float16* Ad = lds + buf * 16384;
#pragma unroll
        for (int i = 0; i < 4; ++i) {
            half8 h;
#pragma unroll
            for (int q = 0; q < 4; ++q) {
                h[q]     = (_Float16)arA[i][0][q];
                h[4 + q] = (_Float16)arA[i][1][q];
            }
            *(half8*)(Ad + (i * 512 + tid) * 8) = h;
        }
    };
    auto stageA16 = [&](int buf, int kt) {
        const _Float16* A = (const _Float16*)Ap;
        _Float16* Ad = lds + buf * 16384;
        const int k0 = kt * 64;
#pragma unroll
        for (int i = 0; i < 4; ++i)
            gld16(A + (size_t)(m0 + rr[i]) * 256 + k0 + cc[i],
                  Ad + (i * 512 + tid) * 8);
    };
    auto stageB = [&](int buf, int kt) {
        _Float16* Bd = lds + 32768 + buf * 16384;
        const int k0 = kt * 64;
#pragma unroll
        for (int i = 0; i < 4; ++i)
            gld16(W + (size_t)(n0 + rr[i]) * 256 + k0 + cc[i],
                  Bd + (i * 512 + tid) * 8);
    };

    f32x4 acc[8][4] = {};

    if (A_F32) { issueA32(0); stageB(0, 0); writeA32(0); }
    else       { stageA16(0, 0); stageB(0, 0); }

#pragma unroll
    for (int kt = 0; kt < 4; ++kt) {
        const int cb = kt & 1, nb = cb ^ 1;
        if (kt < 3) {
            if (A_F32) issueA32(kt + 1); else stageA16(nb, kt + 1);
            stageB(nb, kt + 1);
        }
        if (kt < 3) { if (A_F32) WAITV(12); else WAITV(8); }
        else        { WAITV(0); }
        SBAR();
        const _Float16* Ab = lds + cb * 16384;
        const _Float16* Bb = lds + 32768 + cb * 16384;
#pragma unroll
        for (int kk = 0; kk < 2; ++kk) {
            half8 af[8], bf[4];
#pragma unroll
            for (int mi = 0; mi < 8; ++mi) {
                const int R = wr + mi * 16 + l15;
                af[mi] = *(const half8*)(Ab + R * 64 + (((kk * 4 + lhi) ^ (R & 7)) * 8));
            }
#pragma unroll
            for (int nj = 0; nj < 4; ++nj) {
                const int R = wc + nj * 16 + l15;
                bf[nj] = *(const half8*)(Bb + R * 64 + (((kk * 4 + lhi) ^ (R & 7)) * 8));
            }
#pragma unroll
            for (int mi = 0; mi < 8; ++mi)
#pragma unroll
                for (int nj = 0; nj < 4; ++nj)
                    acc[mi][nj] = MFMA16(af[mi], bf[nj], acc[mi][nj]);
        }
        SBAR();
        if (A_F32 && kt < 3) writeA32(nb);
    }

    // ---------------- epilogue ----------------
    const bool hi = DUAL && (y == 1);
    void* Cp = hi ? C1 : C0;
    const int cadj = hi ? 256 : 0;

    _Float16* Cst = lds;   // [128][264]
#pragma unroll
    for (int h = 0; h < 2; ++h) {
        if ((wid >> 2) == h) {
#pragma unroll
            for (int mi = 0; mi < 8; ++mi) {
#pragma unroll
                for (int nj = 0; nj < 4; ++nj) {
                    const int col = wc + nj * 16 + l15;
                    const float bv = ADD_BIAS ? bias[n0 + col - cadj] : 0.0f;
#pragma unroll
                    for (int j = 0; j < 4; ++j)
                        Cst[(mi * 16 + lhi * 4 + j) * 264 + col] =
                            (_Float16)(acc[mi][nj][j] + bv);
                }
            }
        }
        __syncthreads();
        const int r  = tid >> 2;
        const int c0 = (tid & 3) * 64;
        const int grow = m0 + h * 128 + r;
        int orow;
        if (DUAL)             orow = hi ? grow : map_ln_nl(grow);
        else if (ROWMAP == 1) orow = map_ln_nl(grow);
        else                  orow = grow;
        _Float16* dst = (_Float16*)Cp + (size_t)orow * 256 + (n0 - cadj) + c0;
        const _Float16* srcp = Cst + r * 264 + c0;
#pragma unroll
        for (int u = 0; u < 8; ++u)
            *(half8*)(dst + u * 8) = *(const half8*)(srcp + u * 8);
        __syncthreads();
    }
}

// ---------------- temporal attention: per (b,n,h), seq = L = 128, NL layout ----------------
// Swapped QK^T (st = P[q][k], lane l15=q, regs k).  PV via 16x16x16 MFMA:
// A-operand layout (l15=row, k=lhi*4+j) == our st layout -> pa = cvt(st) in
// registers.  NO P LDS buffer at all; only V^T (8.7 KB) -> high occupancy.
__global__ __launch_bounds__(256) void attn_temporal(
    const _Float16* __restrict__ Q, const _Float16* __restrict__ K,
    const _Float16* __restrict__ V, _Float16* __restrict__ O)
{
    __shared__ __align__(16) _Float16 Vt[32][136];   // V^T: [d][l]

    const int tid  = threadIdx.x;
    const int lane = tid & 63;
    const int l15  = lane & 15;
    const int lhi  = lane >> 4;
    const int wid  = tid >> 6;
    const int bidx = blockIdx.x;
    const int h = bidx & 7;
    const int n = (bidx >> 3) & 63;
    const int b = bidx >> 9;
    const size_t base = ((size_t)(b * 64 + n) * 128) * 256 + (size_t)h * 32;

    // cooperative V transpose into LDS
    {
        const int l  = tid >> 1;
        const int dh = (tid & 1) * 16;
        const _Float16* srcp = V + base + (size_t)l * 256 + dh;
        half8 v0 = *(const half8*)(srcp);
        half8 v1 = *(const half8*)(srcp + 8);
#pragma unroll
        for (int j = 0; j < 8; ++j) {
            Vt[dh + j][l]     = v0[j];
            Vt[dh + 8 + j][l] = v1[j];
        }
    }
    __syncthreads();

    // S^T = K Q^T : wave owns q-cols [wid*32, wid*32+32), all 128 k-rows
    half8 qf[2];
#pragma unroll
    for (int ct = 0; ct < 2; ++ct)
        qf[ct] = *(const half8*)(Q + base +
                  (size_t)(wid * 32 + ct * 16 + l15) * 256 + lhi * 8);
    f32x4 st[2][8] = {};
#pragma unroll
    for (int rt = 0; rt < 8; ++rt) {
        half8 kf = *(const half8*)(K + base +
                    (size_t)(rt * 16 + l15) * 256 + lhi * 8);
#pragma unroll
        for (int ct = 0; ct < 2; ++ct)
            st[ct][rt] = MFMA16(kf, qf[ct], st[ct][rt]);
    }

    // softmax per q (in-lane + shfl 16/32); st <- P (prob, already /sum)
    const float scale = 0.17677669529663687f;  // 1/sqrt(32)
#pragma unroll
    for (int ct = 0; ct < 2; ++ct) {
        float m = st[ct][0][0];
#pragma unroll
        for (int rt = 0; rt < 8; ++rt)
#pragma unroll
            for (int j = 0; j < 4; ++j) m = fmaxf(m, st[ct][rt][j]);
        m = fmaxf(m, __shfl_xor(m, 16));
        m = fmaxf(m, __shfl_xor(m, 32));
        float sum = 0.0f;
#pragma unroll
        for (int rt = 0; rt < 8; ++rt)
#pragma unroll
            for (int j = 0; j < 4; ++j) {
                const float p = __expf((st[ct][rt][j] - m) * scale);
                st[ct][rt][j] = p;
                sum += p;
            }
        sum += __shfl_xor(sum, 16);
        sum += __shfl_xor(sum, 32);
        const float inv = 1.0f / sum;
#pragma unroll
        for (int rt = 0; rt < 8; ++rt)
#pragma unroll
            for (int j = 0; j < 4; ++j) st[ct][rt][j] *= inv;
    }

    // O = P V via K=16 MFMA, P straight from registers
    f32x4 o[2][2] = {};
#pragma unroll
    for (int rt = 0; rt < 8; ++rt) {
        half4 pa[2];
#pragma unroll
        for (int ct = 0; ct < 2; ++ct) {
            half4 t;
#pragma unroll
            for (int j = 0; j < 4; ++j) t[j] = (_Float16)st[ct][rt][j];
            pa[ct] = t;
        }
#pragma unroll
        for (int dt = 0; dt < 2; ++dt) {
            half4 vb = *(const half4*)(&Vt[dt * 16 + l15][rt * 16 + lhi * 4]);
#pragma unroll
            for (int ct = 0; ct < 2; ++ct)
                o[ct][dt] = MFMA16K16(pa[ct], vb, o[ct][dt]);
        }
    }
#pragma unroll
    for (int ct = 0; ct < 2; ++ct)
#pragma unroll
        for (int dt = 0; dt < 2; ++dt)
#pragma unroll
            for (int j = 0; j < 4; ++j)
                O[base + (size_t)(wid * 32 + ct * 16 + lhi * 4 + j) * 256 +
                  dt * 16 + l15] = (_Float16)o[ct][dt][j];
}

// ---------------- fused social stage: per (b,l), 8 waves = 8 heads ----------------
// Qs = Ot@W2^T + b2, attention over N=64 (P in regs via K=16 MFMA),
// out = O@s_wd^T + s_bd stored directly (fp32).
// LDS (halfs): R_A [0,18432): Ot[64][264] -> V^T 8x[32][72] -> O_lds[64][264]
//              R_B [18432,38912): Qs 8x[64][40].   Total 76 KB -> 2 blocks/CU.
__global__ __launch_bounds__(512, 4) void attn_social_fused(
    const _Float16* __restrict__ Ot,   // NL (b,n,l,d) fp16
    const _Float16* __restrict__ Ks,   // LN fp16
    const _Float16* __restrict__ Vs,   // LN fp16
    const _Float16* __restrict__ W2,   // fp16 [256][256]
    const float*    __restrict__ b2,   // fp32 [256]
    const _Float16* __restrict__ Wd,   // s_wd fp16 [256][256]
    const float*    __restrict__ bd,   // s_bd fp32 [256]
    float* __restrict__ out)           // LN fp32
{
    __shared__ __align__(16) _Float16 lds[38912];   // 76 KB

    const int tid  = threadIdx.x;
    const int lane = tid & 63;
    const int l15  = lane & 15;
    const int lhi  = lane >> 4;
    const int h    = tid >> 6;          // wave = head
    const int l = blockIdx.x & 127;
    const int b = blockIdx.x >> 7;

    _Float16* Ot_lds = lds;                        // [64][264]
    _Float16* Vt_h   = lds + h * 2304;             // [32][72] (after BAR2)
    _Float16* Qs_h   = lds + 18432 + h * 2560;     // [64][40]
    _Float16* O_lds  = lds;                        // [64][264] (after BAR3)

    const size_t kvbase = ((size_t)(b * 128 + l) * 64) * 256;

    // ---- phase 1: stage Ot slice: tokens (b, n, l), n = 0..63 ----
#pragma unroll
    for (int i = 0; i < 4; ++i) {
        const int chunk = i * 512 + tid;           // 2048 chunks of 8 halfs
        const int r  = chunk >> 5;
        const int c8 = (chunk & 31) * 8;
        half8 v = *(const half8*)(Ot + ((size_t)(b * 64 + r) * 128 + l) * 256 + c8);
        *(half8*)(Ot_lds + r * 264 + c8) = v;
    }
    __syncthreads();                               // BAR1

    // ---- phase 2: Qs_h = Ot @ W2_h^T + b2_h  (D: row=d', col=token) ----
    {
        float b2v[2][4];
#pragma unroll
        for (int mt = 0; mt < 2; ++mt)
#pragma unroll
            for (int j = 0; j < 4; ++j)
                b2v[mt][j] = b2[h * 32 + mt * 16 + lhi * 4 + j];

        f32x4 qacc[2][4] = {};
#pragma unroll
        for (int ks = 0; ks < 8; ++ks) {
            half8 wf[2], of[4];
#pragma unroll
            for (int mt = 0; mt < 2; ++mt)
                wf[mt] = *(const half8*)(W2 + (size_t)(h * 32 + mt * 16 + l15) * 256 + ks * 32 + lhi * 8);
#pragma unroll
            for (int tg = 0; tg < 4; ++tg)
                of[tg] = *(const half8*)(Ot_lds + (tg * 16 + l15) * 264 + ks * 32 + lhi * 8);
#pragma unroll
            for (int mt = 0; mt < 2; ++mt)
#pragma unroll
                for (int tg = 0; tg < 4; ++tg)
                    qacc[mt][tg] = MFMA16(wf[mt], of[tg], qacc[mt][tg]);
        }
#pragma unroll
        for (int mt = 0; mt < 2; ++mt)
#pragma unroll
            for (int tg = 0; tg < 4; ++tg) {
                half4 hv;
#pragma unroll
                for (int j = 0; j < 4; ++j)
                    hv[j] = (_Float16)(qacc[mt][tg][j] + b2v[mt][j]);
                *(half4*)(Qs_h + (tg * 16 + l15) * 40 + mt * 16 + lhi * 4) = hv;
            }
    }
    __syncthreads();                               // BAR2 (Ot region freed)

    // ---- phase 3a: stage V^T for this head (per-wave private region) ----
    {
        half8 vv[4];
#pragma unroll
        for (int i = 0; i < 4; ++i)
            vv[i] = *(const half8*)(Vs + kvbase + (size_t)lane * 256 + h * 32 + i * 8);
#pragma unroll
        for (int i = 0; i < 4; ++i)
#pragma unroll
            for (int j = 0; j < 8; ++j)
                Vt_h[(i * 8 + j) * 72 + lane] = vv[i][j];
    }

    // ---- phase 3b: S^T = Ks_h . Qs_h (lane l15 = q, regs = k) ----
    half8 qf[4];
#pragma unroll
    for (int g = 0; g < 4; ++g)
        qf[g] = *(const half8*)(Qs_h + (g * 16 + l15) * 40 + lhi * 8);
    f32x4 st[4][4] = {};
#pragma unroll
    for (int rt = 0; rt < 4; ++rt) {
        half8 kf = *(const half8*)(Ks + kvbase + (size_t)(rt * 16 + l15) * 256 + h * 32 + lhi * 8);
#pragma unroll
        for (int g = 0; g < 4; ++g)
            st[g][rt] = MFMA16(kf, qf[g], st[g][rt]);
    }

    // ---- phase 3c: softmax per q-col; st <- P ----
    const float scale = 0.17677669529663687f;
#pragma unroll
    for (int g = 0; g < 4; ++g) {
        float m = st[g][0][0];
#pragma unroll
        for (int rt = 0; rt < 4; ++rt)
#pragma unroll
            for (int j = 0; j < 4; ++j) m = fmaxf(m, st[g][rt][j]);
        m = fmaxf(m, __shfl_xor(m, 16));
        m = fmaxf(m, __shfl_xor(m, 32));
        float sum = 0.0f;
#pragma unroll
        for (int rt = 0; rt < 4; ++rt)
#pragma unroll
            for (int j = 0; j < 4; ++j) {
                const float p = __expf((st[g][rt][j] - m) * scale);
                st[g][rt][j] = p;
                sum += p;
            }
        sum += __shfl_xor(sum, 16);
        sum += __shfl_xor(sum, 32);
        const float inv = 1.0f / sum;
#pragma unroll
        for (int rt = 0; rt < 4; ++rt)
#pragma unroll
            for (int j = 0; j < 4; ++j) st[g][rt][j] *= inv;
    }

    // ---- phase 3d: O_h = P V via K=16 MFMA, P from registers ----
    f32x4 o[4][2] = {};
#pragma unroll
    for (int rt = 0; rt < 4; ++rt) {
        half4 vb[2];
#pragma unroll
        for (int dt = 0; dt < 2; ++dt)
            vb[dt] = *(const half4*)(Vt_h + (dt * 16 + l15) * 72 + rt * 16 + lhi * 4);
#pragma unroll
        for (int g = 0; g < 4; ++g) {
            half4 pa;
#pragma unroll
            for (int j = 0; j < 4; ++j) pa[j] = (_Float16)st[g][rt][j];
#pragma unroll
            for (int dt = 0; dt < 2; ++dt)
                o[g][dt] = MFMA16K16(pa, vb[dt], o[g][dt]);
        }
    }
    __syncthreads();                               // BAR3 (Vt region freed)

    // ---- phase 4: O -> LDS [token][d], heads side by side ----
#pragma unroll
    for (int g = 0; g < 4; ++g)
#pragma unroll
        for (int dt = 0; dt < 2; ++dt)
#pragma unroll
            for (int j = 0; j < 4; ++j)
                O_lds[(g * 16 + lhi * 4 + j) * 264 + h * 32 + dt * 16 + l15] =
                    (_Float16)o[g][dt][j];
    __syncthreads();                               // BAR4

    // ---- phase 5: out = O @ s_wd^T + bd; direct fp32 stores ----
    {
        f32x4 oc[4][2] = {};
#pragma unroll
        for (int ks = 0; ks < 8; ++ks) {
            half8 af[4], wf2[2];
#pragma unroll
            for (int g2 = 0; g2 < 4; ++g2)
                af[g2] = *(const half8*)(O_lds + (g2 * 16 + l15) * 264 + ks * 32 + lhi * 8);
#pragma unroll
            for (int nt = 0; nt < 2; ++nt)
                wf2[nt] = *(const half8*)(Wd + (size_t)(h * 32 + nt * 16 + l15) * 256 + ks * 32 + lhi * 8);
#pragma unroll
            for (int g2 = 0; g2 < 4; ++g2)
#pragma unroll
                for (int nt = 0; nt < 2; ++nt)
                    oc[g2][nt] = MFMA16(af[g2], wf2[nt], oc[g2][nt]);
        }
        const float bdv[2] = { bd[h * 32 + l15], bd[h * 32 + 16 + l15] };
        float* outb = out + ((size_t)(b * 128 + l) * 64) * 256;
#pragma unroll
        for (int g2 = 0; g2 < 4; ++g2)
#pragma unroll
            for (int nt = 0; nt < 2; ++nt)
#pragma unroll
                for (int j = 0; j < 4; ++j)
                    outb[(size_t)(g2 * 16 + lhi * 4 + j) * 256 +
                         h * 32 + nt * 16 + l15] = oc[g2][nt][j] + bdv[nt];
    }
}

// ---------------- host launch ----------------
extern "C" void kernel_launch(void* const* d_in, const int* in_sizes, int n_in,
                              void* d_out, int out_size, void* d_ws, size_t ws_size,
                              hipStream_t stream)
{
    const float* q    = (const float*)d_in[0];
    const float* k    = (const float*)d_in[1];
    const float* v    = (const float*)d_in[2];
    const float* t_wq = (const float*)d_in[3];
    const float* t_wk = (const float*)d_in[4];
    const float* t_wv = (const float*)d_in[5];
    const float* t_wd = (const float*)d_in[6];
    const float* t_bd = (const float*)d_in[7];
    const float* s_wq = (const float*)d_in[8];
    const float* s_wk = (const float*)d_in[9];
    const float* s_wv = (const float*)d_in[10];
    const float* s_wd = (const float*)d_in[11];
    const float* s_bd = (const float*)d_in[12];

    // workspace: 7 fp16 weight slots + b2 (fp32) + 6 activation slots (32 MB)
    _Float16* Wb = (_Float16*)d_ws;
    float* b2 = (float*)(Wb + 7 * 65536);
    const size_t SLOT = (size_t)65536 * 256;
    _Float16* S0 = (_Float16*)(b2 + 256);
    _Float16* S1 = S0 + SLOT;
    _Float16* S2 = S0 + 2 * SLOT;
    _Float16* S3 = S0 + 3 * SLOT;
    _Float16* S4 = S0 + 4 * SLOT;
    _Float16* S5 = S0 + 5 * SLOT;

    cvt_weights<<<dim3(256, 6), 256, 0, stream>>>(
        t_wq, t_wk, s_wk, t_wv, s_wv, s_wd, Wb);
    make_w2<<<256, 256, 0, stream>>>(s_wq, t_wd, t_bd, Wb + 5 * 65536, b2);

    // Qt(NL) = q @ t_wq^T -> S1   (fp32 A read directly)
    gemm16<true, 1, false, false, false><<<256, 512, 0, stream>>>(
        q, Wb + 0 * 65536, nullptr, S1, nullptr);
    // Kt(NL) -> S2, Ks(LN) -> S3  (dual over [t_wk; s_wk])
    gemm16<true, 1, true, false, false><<<512, 512, 0, stream>>>(
        k, Wb + 1 * 65536, nullptr, S2, S3);
    // Vt(NL) -> S4, Vs(LN) -> S5
    gemm16<true, 1, true, false, false><<<512, 512, 0, stream>>>(
        v, Wb + 3 * 65536, nullptr, S4, S5);

    attn_temporal<<<4096, 256, 0, stream>>>(S1, S2, S4, S0);   // Ot(NL) -> S0

    // fused: Qs-proj + social attention + out-proj
    attn_social_fused<<<1024, 512, 0, stream>>>(
        S0, S3, S5, Wb + 5 * 65536, b2, Wb + 6 * 65536, s_bd, (float*)d_out);

    (void)in_sizes; (void)n_in; (void)out_size; (void)ws_size;
}

// Round 10
// 261.776 us; speedup vs baseline: 1.6102x; 1.0021x over previous
//
#include <hip/hip_runtime.h>

typedef __attribute__((ext_vector_type(8))) _Float16 half8;
typedef __attribute__((ext_vector_type(4))) _Float16 half4;
typedef __attribute__((ext_vector_type(4))) float f32x4;

#define MFMA16(a, b, c) __builtin_amdgcn_mfma_f32_16x16x32_f16((a), (b), (c), 0, 0, 0)
#define MFMA16K16(a, b, c) __builtin_amdgcn_mfma_f32_16x16x16f16((a), (b), (c), 0, 0, 0)

#define WAITV(N) asm volatile("s_waitcnt vmcnt(" #N ") lgkmcnt(0)" ::: "memory")
#define SBAR()   asm volatile("s_barrier" ::: "memory")

// B=8, L=128, N=64, D=256, H=8, dk=32.  M = 65536 tokens.
// Token orders: LN = (b,l,n), NL = (b,n,l).

__device__ inline int map_ln_nl(int t) {   // (b,l,n) -> (b,n,l)
    return (t & ~8191) | ((t & 63) << 7) | ((t >> 6) & 127);
}

typedef const __attribute__((address_space(1))) unsigned int guint;
typedef __attribute__((address_space(3))) unsigned int luint;
__device__ inline void gld16(const _Float16* g, _Float16* l) {
    __builtin_amdgcn_global_load_lds((guint*)g, (luint*)l, 16, 0, 0);
}

// ---------------- weight fp32 -> fp16 ----------------
// slots: 0=t_wq 1=t_wk 2=s_wk 3=t_wv 4=s_wv 5=W2(made elsewhere) 6=s_wd
__global__ __launch_bounds__(256) void cvt_weights(
    const float* __restrict__ w0, const float* __restrict__ w1,
    const float* __restrict__ w2, const float* __restrict__ w3,
    const float* __restrict__ w4, const float* __restrict__ w5,
    _Float16* __restrict__ out)
{
    const float* src[6] = {w0, w1, w2, w3, w4, w5};
    const int m = blockIdx.y;
    const int slot = (m < 5) ? m : 6;
    const int i = blockIdx.x * 256 + threadIdx.x;
    out[(size_t)slot * 65536 + i] = (_Float16)src[m][i];
}

// ---------------- W2 = s_wq @ t_wd (fp32 accum), b2 = s_wq @ t_bd ----------------
__global__ __launch_bounds__(256) void make_w2(
    const float* __restrict__ s_wq, const float* __restrict__ t_wd,
    const float* __restrict__ t_bd, _Float16* __restrict__ W2,
    float* __restrict__ b2)
{
    const int e = blockIdx.x;
    const int d = threadIdx.x;
    float acc = 0.0f;
    for (int c = 0; c < 256; ++c)
        acc = fmaf(s_wq[e * 256 + c], t_wd[c * 256 + d], acc);
    W2[e * 256 + d] = (_Float16)acc;
    if (d == 0) {
        float bb = 0.0f;
        for (int c = 0; c < 256; ++c) bb = fmaf(s_wq[e * 256 + c], t_bd[c], bb);
        b2[e] = bb;
    }
}

// ---------------- trio GEMM: 3x { C[M,256] = A[M,256] @ W[256,256]^T } ----------------
// R7 structure: 256x256 tile, BK=64, 8 waves, counted vmcnt.  Block p = wg/256
// selects (A, W, C).  All A fp32, all C fp16 with LN->NL row map.
__global__ __launch_bounds__(512, 2) void gemm_trio(
    const float* __restrict__ A0, const float* __restrict__ A1,
    const float* __restrict__ A2, const _Float16* __restrict__ W0,
    const _Float16* __restrict__ W1, const _Float16* __restrict__ W2,
    _Float16* __restrict__ C0, _Float16* __restrict__ C1,
    _Float16* __restrict__ C2)
{
    __shared__ __align__(16) _Float16 lds[65536];   // 128 KB

    const int tid  = threadIdx.x;
    const int lane = tid & 63;
    const int l15  = lane & 15;
    const int lhi  = lane >> 4;
    const int wid  = tid >> 6;
    const int wg   = (blockIdx.x & 7) * 96 + (blockIdx.x >> 3);   // nwg=768
    const int p    = wg >> 8;
    const int x    = wg & 255;
    const int m0   = x * 256;
    const int wr   = (wid >> 2) * 128;
    const int wc   = (wid & 3) * 64;

    const float* Ap; const _Float16* Wp; _Float16* Cp;
    if (p == 0)      { Ap = A0; Wp = W0; Cp = C0; }
    else if (p == 1) { Ap = A1; Wp = W1; Cp = C1; }
    else             { Ap = A2; Wp = W2; Cp = C2; }

    int rr[4], cc[4];
#pragma unroll
    for (int i = 0; i < 4; ++i) {
        const int c = i * 512 + tid;
        const int r = c >> 3;
        rr[i] = r;
        cc[i] = ((c & 7) ^ (r & 7)) * 8;   // pre-swizzled column
    }

    f32x4 arA[4][2];

    auto issueA32 = [&](int kt) {
        const int k0 = kt * 64;
#pragma unroll
        for (int i = 0; i < 4; ++i) {
            const float* pp = Ap + (size_t)(m0 + rr[i]) * 256 + k0 + cc[i];
            arA[i][0] = *(const f32x4*)(pp);
            arA[i][1] = *(const f32x4*)(pp + 4);
        }
    };
    auto writeA32 = [&](int buf) {
        _Float16* Ad = lds + buf * 16384;
#pragma unroll
        for (int i = 0; i < 4; ++i) {
            half8 h;
#pragma unroll
            for (int q = 0; q < 4; ++q) {
                h[q]     = (_Float16)arA[i][0][q];
                h[4 + q] = (_Float16)arA[i][1][q];
            }
            *(half8*)(Ad + (i * 512 + tid) * 8) = h;
        }
    };
    auto stageB = [&](int buf, int kt) {
        _Float16* Bd = lds + 32768 + buf * 16384;
        const int k0 = kt * 64;
#pragma unroll
        for (int i = 0; i < 4; ++i)
            gld16(Wp + (size_t)rr[i] * 256 + k0 + cc[i],
                  Bd + (i * 512 + tid) * 8);
    };

    f32x4 acc[8][4] = {};

    issueA32(0); stageB(0, 0); writeA32(0);

#pragma unroll
    for (int kt = 0; kt < 4; ++kt) {
        const int cb = kt & 1, nb = cb ^ 1;
        if (kt < 3) { issueA32(kt + 1); stageB(nb, kt + 1); }
        if (kt < 3) WAITV(12); else WAITV(0);
        SBAR();
        const _Float16* Ab = lds + cb * 16384;
        const _Float16* Bb = lds + 32768 + cb * 16384;
#pragma unroll
        for (int kk = 0; kk < 2; ++kk) {
            half8 af[8], bf[4];
#pragma unroll
            for (int mi = 0; mi < 8; ++mi) {
                const int R = wr + mi * 16 + l15;
                af[mi] = *(const half8*)(Ab + R * 64 + (((kk * 4 + lhi) ^ (R & 7)) * 8));
            }
#pragma unroll
            for (int nj = 0; nj < 4; ++nj) {
                const int R = wc + nj * 16 + l15;
                bf[nj] = *(const half8*)(Bb + R * 64 + (((kk * 4 + lhi) ^ (R & 7)) * 8));
            }
#pragma unroll
            for (int mi = 0; mi < 8; ++mi)
#pragma unroll
                for (int nj = 0; nj < 4; ++nj)
                    acc[mi][nj] = MFMA16(af[mi], bf[nj], acc[mi][nj]);
        }
        SBAR();
        if (kt < 3) writeA32(nb);
    }

    // epilogue: LDS restage, full-row half8 stores, LN->NL row map
    _Float16* Cst = lds;   // [128][264]
#pragma unroll
    for (int hh = 0; hh < 2; ++hh) {
        if ((wid >> 2) == hh) {
#pragma unroll
            for (int mi = 0; mi < 8; ++mi) {
#pragma unroll
                for (int nj = 0; nj < 4; ++nj) {
                    const int col = wc + nj * 16 + l15;
#pragma unroll
                    for (int j = 0; j < 4; ++j)
                        Cst[(mi * 16 + lhi * 4 + j) * 264 + col] =
                            (_Float16)acc[mi][nj][j];
                }
            }
        }
        __syncthreads();
        const int r  = tid >> 2;
        const int c0 = (tid & 3) * 64;
        const int orow = map_ln_nl(m0 + hh * 128 + r);
        _Float16* dst = Cp + (size_t)orow * 256 + c0;
        const _Float16* srcp = Cst + r * 264 + c0;
#pragma unroll
        for (int u = 0; u < 8; ++u)
            *(half8*)(dst + u * 8) = *(const half8*)(srcp + u * 8);
        __syncthreads();
    }
}

// ---------------- temporal attention: per (b,n,h), seq = L = 128, NL layout ----------------
// Swapped QK^T; softmax in regs; PV via K=16 MFMA with P in registers.
__global__ __launch_bounds__(256) void attn_temporal(
    const _Float16* __restrict__ Q, const _Float16* __restrict__ K,
    const _Float16* __restrict__ V, _Float16* __restrict__ O)
{
    __shared__ __align__(16) _Float16 Vt[32][136];   // V^T: [d][l]

    const int tid  = threadIdx.x;
    const int lane = tid & 63;
    const int l15  = lane & 15;
    const int lhi  = lane >> 4;
    const int wid  = tid >> 6;
    const int bidx = blockIdx.x;
    const int h = bidx & 7;
    const int n = (bidx >> 3) & 63;
    const int b = bidx >> 9;
    const size_t base = ((size_t)(b * 64 + n) * 128) * 256 + (size_t)h * 32;

    {
        const int l  = tid >> 1;
        const int dh = (tid & 1) * 16;
        const _Float16* srcp = V + base + (size_t)l * 256 + dh;
        half8 v0 = *(const half8*)(srcp);
        half8 v1 = *(const half8*)(srcp + 8);
#pragma unroll
        for (int j = 0; j < 8; ++j) {
            Vt[dh + j][l]     = v0[j];
            Vt[dh + 8 + j][l] = v1[j];
        }
    }
    __syncthreads();

    half8 qf[2];
#pragma unroll
    for (int ct = 0; ct < 2; ++ct)
        qf[ct] = *(const half8*)(Q + base +
                  (size_t)(wid * 32 + ct * 16 + l15) * 256 + lhi * 8);
    f32x4 st[2][8] = {};
#pragma unroll
    for (int rt = 0; rt < 8; ++rt) {
        half8 kf = *(const half8*)(K + base +
                    (size_t)(rt * 16 + l15) * 256 + lhi * 8);
#pragma unroll
        for (int ct = 0; ct < 2; ++ct)
            st[ct][rt] = MFMA16(kf, qf[ct], st[ct][rt]);
    }

    const float scale = 0.17677669529663687f;  // 1/sqrt(32)
#pragma unroll
    for (int ct = 0; ct < 2; ++ct) {
        float m = st[ct][0][0];
#pragma unroll
        for (int rt = 0; rt < 8; ++rt)
#pragma unroll
            for (int j = 0; j < 4; ++j) m = fmaxf(m, st[ct][rt][j]);
        m = fmaxf(m, __shfl_xor(m, 16));
        m = fmaxf(m, __shfl_xor(m, 32));
        float sum = 0.0f;
#pragma unroll
        for (int rt = 0; rt < 8; ++rt)
#pragma unroll
            for (int j = 0; j < 4; ++j) {
                const float p = __expf((st[ct][rt][j] - m) * scale);
                st[ct][rt][j] = p;
                sum += p;
            }
        sum += __shfl_xor(sum, 16);
        sum += __shfl_xor(sum, 32);
        const float inv = 1.0f / sum;
#pragma unroll
        for (int rt = 0; rt < 8; ++rt)
#pragma unroll
            for (int j = 0; j < 4; ++j) st[ct][rt][j] *= inv;
    }

    f32x4 o[2][2] = {};
#pragma unroll
    for (int rt = 0; rt < 8; ++rt) {
        half4 pa[2];
#pragma unroll
        for (int ct = 0; ct < 2; ++ct) {
            half4 t;
#pragma unroll
            for (int j = 0; j < 4; ++j) t[j] = (_Float16)st[ct][rt][j];
            pa[ct] = t;
        }
#pragma unroll
        for (int dt = 0; dt < 2; ++dt) {
            half4 vb = *(const half4*)(&Vt[dt * 16 + l15][rt * 16 + lhi * 4]);
#pragma unroll
            for (int ct = 0; ct < 2; ++ct)
                o[ct][dt] = MFMA16K16(pa[ct], vb, o[ct][dt]);
        }
    }
#pragma unroll
    for (int ct = 0; ct < 2; ++ct)
#pragma unroll
        for (int dt = 0; dt < 2; ++dt)
#pragma unroll
            for (int j = 0; j < 4; ++j)
                O[base + (size_t)(wid * 32 + ct * 16 + lhi * 4 + j) * 256 +
                  dt * 16 + l15] = (_Float16)o[ct][dt][j];
}

// ---------------- fused social stage: per (b,l), 8 waves = 8 heads ----------------
// In-block: Qs = Ot@W2^T+b2, Ks = k@s_wk^T, Vs = v@s_wv^T (k,v fp32 slices),
// attention over N=64 (P in regs), out = O@s_wd^T + s_bd (fp32 direct).
// LDS (halfs): RA [0,16896): staging [64][264] (Ot -> k -> v -> O)
//              Qs 8x[64][40] at 16896;  Ks 8x[64][40] at 37376 (-> V^T [32][72])
__global__ __launch_bounds__(512, 2) void attn_social_fused(
    const _Float16* __restrict__ Ot,   // NL (b,n,l,d) fp16
    const float* __restrict__ kin,     // LN fp32 (original input)
    const float* __restrict__ vin,     // LN fp32
    const _Float16* __restrict__ W2, const float* __restrict__ b2,
    const _Float16* __restrict__ Wk, const _Float16* __restrict__ Wv,
    const _Float16* __restrict__ Wd, const float* __restrict__ bd,
    float* __restrict__ out)           // LN fp32
{
    __shared__ __align__(16) _Float16 lds[57856];   // 113 KB

    const int tid  = threadIdx.x;
    const int lane = tid & 63;
    const int l15  = lane & 15;
    const int lhi  = lane >> 4;
    const int h    = tid >> 6;          // wave = head
    const int l = blockIdx.x & 127;
    const int b = blockIdx.x >> 7;

    _Float16* RA   = lds;                      // [64][264]
    _Float16* Qs_h = lds + 16896 + h * 2560;   // [64][40]
    _Float16* Kb_h = lds + 37376 + h * 2560;   // [64][40]; later V^T [32][72]
    const size_t tok0 = (size_t)(b * 128 + l) * 64;

    auto stage_f32 = [&](const float* src) {
#pragma unroll
        for (int i = 0; i < 4; ++i) {
            const int chunk = i * 512 + tid;
            const int r  = chunk >> 5;
            const int c8 = (chunk & 31) * 8;
            const float* p = src + (tok0 + r) * 256 + c8;
            f32x4 a = *(const f32x4*)(p);
            f32x4 c = *(const f32x4*)(p + 4);
            half8 hv;
#pragma unroll
            for (int j = 0; j < 4; ++j) { hv[j] = (_Float16)a[j]; hv[4 + j] = (_Float16)c[j]; }
            *(half8*)(RA + r * 264 + c8) = hv;
        }
    };

    // proj: D[token][d'] = RA[64 tok][256] @ Wrow[h*32..+32][256]^T (+bias)
    auto proj32 = [&](const _Float16* Wp, const float* bias, _Float16* dst) {
        f32x4 qacc[2][4] = {};
#pragma unroll
        for (int ks = 0; ks < 8; ++ks) {
            half8 wf[2], af[4];
#pragma unroll
            for (int mt = 0; mt < 2; ++mt)
                wf[mt] = *(const half8*)(Wp + (size_t)(h * 32 + mt * 16 + l15) * 256 + ks * 32 + lhi * 8);
#pragma unroll
            for (int tg = 0; tg < 4; ++tg)
                af[tg] = *(const half8*)(RA + (tg * 16 + l15) * 264 + ks * 32 + lhi * 8);
#pragma unroll
            for (int mt = 0; mt < 2; ++mt)
#pragma unroll
                for (int tg = 0; tg < 4; ++tg)
                    qacc[mt][tg] = MFMA16(wf[mt], af[tg], qacc[mt][tg]);
        }
#pragma unroll
        for (int mt = 0; mt < 2; ++mt) {
            float bv[4] = {0.f, 0.f, 0.f, 0.f};
            if (bias) {
#pragma unroll
                for (int j = 0; j < 4; ++j) bv[j] = bias[h * 32 + mt * 16 + lhi * 4 + j];
            }
#pragma unroll
            for (int tg = 0; tg < 4; ++tg) {
                half4 hv;
#pragma unroll
                for (int j = 0; j < 4; ++j) hv[j] = (_Float16)(qacc[mt][tg][j] + bv[j]);
                *(half4*)(dst + (tg * 16 + l15) * 40 + mt * 16 + lhi * 4) = hv;
            }
        }
    };

    // P1: stage Ot slice (NL rows: (b,n,l))
#pragma unroll
    for (int i = 0; i < 4; ++i) {
        const int chunk = i * 512 + tid;
        const int r  = chunk >> 5;
        const int c8 = (chunk & 31) * 8;
        half8 v = *(const half8*)(Ot + ((size_t)(b * 64 + r) * 128 + l) * 256 + c8);
        *(half8*)(RA + r * 264 + c8) = v;
    }
    __syncthreads();                               // BAR1

    // P2: Qs
    proj32(W2, b2, Qs_h);
    __syncthreads();                               // BAR2 (RA free)

    // P3: stage k (fp32 -> fp16)
    stage_f32(kin);
    __syncthreads();                               // BAR3

    // P4: Ks
    proj32(Wk, nullptr, Kb_h);

    // P5: S^T = Ks . Qs (lane l15 = q, regs = k) + softmax -> P in regs
    half8 qf[4];
#pragma unroll
    for (int g = 0; g < 4; ++g)
        qf[g] = *(const half8*)(Qs_h + (g * 16 + l15) * 40 + lhi * 8);
    f32x4 st[4][4] = {};
#pragma unroll
    for (int rt = 0; rt < 4; ++rt) {
        half8 kf = *(const half8*)(Kb_h + (rt * 16 + l15) * 40 + lhi * 8);
#pragma unroll
        for (int g = 0; g < 4; ++g)
            st[g][rt] = MFMA16(kf, qf[g], st[g][rt]);
    }
    const float scale = 0.17677669529663687f;
#pragma unroll
    for (int g = 0; g < 4; ++g) {
        float m = st[g][0][0];
#pragma unroll
        for (int rt = 0; rt < 4; ++rt)
#pragma unroll
            for (int j = 0; j < 4; ++j) m = fmaxf(m, st[g][rt][j]);
        m = fmaxf(m, __shfl_xor(m, 16));
        m = fmaxf(m, __shfl_xor(m, 32));
        float sum = 0.0f;
#pragma unroll
        for (int rt = 0; rt < 4; ++rt)
#pragma unroll
            for (int j = 0; j < 4; ++j) {
                const float p = __expf((st[g][rt][j] - m) * scale);
                st[g][rt][j] = p;
                sum += p;
            }
        sum += __shfl_xor(sum, 16);
        sum += __shfl_xor(sum, 32);
        const float inv = 1.0f / sum;
#pragma unroll
        for (int rt = 0; rt < 4; ++rt)
#pragma unroll
            for (int j = 0; j < 4; ++j) st[g][rt][j] *= inv;
    }
    __syncthreads();                               // BAR4 (RA(k), Ks reads done)

    // P6: stage v (fp32 -> fp16)
    stage_f32(vin);
    __syncthreads();                               // BAR5

    // P7: Vs-proj -> V^T [32 d][72 pad] (reuse Ks region, same wave private)
    _Float16* Vt_h = Kb_h;
    {
        f32x4 vacc[2][4] = {};
#pragma unroll
        for (int ks = 0; ks < 8; ++ks) {
            half8 wf[2], af[4];
#pragma unroll
            for (int mt = 0; mt < 2; ++mt)
                wf[mt] = *(const half8*)(Wv + (size_t)(h * 32 + mt * 16 + l15) * 256 + ks * 32 + lhi * 8);
#pragma unroll
            for (int tg = 0; tg < 4; ++tg)
                af[tg] = *(const half8*)(RA + (tg * 16 + l15) * 264 + ks * 32 + lhi * 8);
#pragma unroll
            for (int mt = 0; mt < 2; ++mt)
#pragma unroll
                for (int tg = 0; tg < 4; ++tg)
                    vacc[mt][tg] = MFMA16(wf[mt], af[tg], vacc[mt][tg]);
        }
#pragma unroll
        for (int mt = 0; mt < 2; ++mt)
#pragma unroll
            for (int tg = 0; tg < 4; ++tg)
#pragma unroll
                for (int j = 0; j < 4; ++j)
                    Vt_h[(mt * 16 + lhi * 4 + j) * 72 + tg * 16 + l15] =
                        (_Float16)vacc[mt][tg][j];
    }

    // P8: O_h = P V via K=16 MFMA (P in regs)
    f32x4 o[4][2] = {};
#pragma unroll
    for (int rt = 0; rt < 4; ++rt) {
        half4 vb[2];
#pragma unroll
        for (int dt = 0; dt < 2; ++dt)
            vb[dt] = *(const half4*)(Vt_h + (dt * 16 + l15) * 72 + rt * 16 + lhi * 4);
#pragma unroll
        for (int g = 0; g < 4; ++g) {
            half4 pa;
#pragma unroll
            for (int j = 0; j < 4; ++j) pa[j] = (_Float16)st[g][rt][j];
#pragma unroll
            for (int dt = 0; dt < 2; ++dt)
                o[g][dt] = MFMA16K16(pa, vb[dt], o[g][dt]);
        }
    }
    __syncthreads();                               // BAR6 (RA(v) reads done)

    // P9: O -> RA [token][d], heads side by side
#pragma unroll
    for (int g = 0; g < 4; ++g)
#pragma unroll
        for (int dt = 0; dt < 2; ++dt)
#pragma unroll
            for (int j = 0; j < 4; ++j)
                RA[(g * 16 + lhi * 4 + j) * 264 + h * 32 + dt * 16 + l15] =
                    (_Float16)o[g][dt][j];
    __syncthreads();                               // BAR7

    // P10: out = O @ s_wd^T + bd; direct fp32 stores
    {
        f32x4 oc[4][2] = {};
#pragma unroll
        for (int ks = 0; ks < 8; ++ks) {
            half8 af[4], wf2[2];
#pragma unroll
            for (int g2 = 0; g2 < 4; ++g2)
                af[g2] = *(const half8*)(RA + (g2 * 16 + l15) * 264 + ks * 32 + lhi * 8);
#pragma unroll
            for (int nt = 0; nt < 2; ++nt)
                wf2[nt] = *(const half8*)(Wd + (size_t)(h * 32 + nt * 16 + l15) * 256 + ks * 32 + lhi * 8);
#pragma unroll
            for (int g2 = 0; g2 < 4; ++g2)
#pragma unroll
                for (int nt = 0; nt < 2; ++nt)
                    oc[g2][nt] = MFMA16(af[g2], wf2[nt], oc[g2][nt]);
        }
        const float bdv[2] = { bd[h * 32 + l15], bd[h * 32 + 16 + l15] };
        float* outb = out + tok0 * 256;
#pragma unroll
        for (int g2 = 0; g2 < 4; ++g2)
#pragma unroll
            for (int nt = 0; nt < 2; ++nt)
#pragma unroll
                for (int j = 0; j < 4; ++j)
                    outb[(size_t)(g2 * 16 + lhi * 4 + j) * 256 +
                         h * 32 + nt * 16 + l15] = oc[g2][nt][j] + bdv[nt];
    }
}

// ---------------- host launch ----------------
extern "C" void kernel_launch(void* const* d_in, const int* in_sizes, int n_in,
                              void* d_out, int out_size, void* d_ws, size_t ws_size,
                              hipStream_t stream)
{
    const float* q    = (const float*)d_in[0];
    const float* k    = (const float*)d_in[1];
    const float* v    = (const float*)d_in[2];
    const float* t_wq = (const float*)d_in[3];
    const float* t_wk = (const float*)d_in[4];
    const float* t_wv = (const float*)d_in[5];
    const float* t_wd = (const float*)d_in[6];
    const float* t_bd = (const float*)d_in[7];
    const float* s_wq = (const float*)d_in[8];
    const float* s_wk = (const float*)d_in[9];
    const float* s_wv = (const float*)d_in[10];
    const float* s_wd = (const float*)d_in[11];
    const float* s_bd = (const float*)d_in[12];

    // workspace: 7 fp16 weight slots + b2 (fp32) + activation slots (32 MB)
    _Float16* Wb = (_Float16*)d_ws;
    float* b2 = (float*)(Wb + 7 * 65536);
    const size_t SLOT = (size_t)65536 * 256;
    _Float16* S0 = (_Float16*)(b2 + 256);
    _Float16* S1 = S0 + SLOT;
    _Float16* S2 = S0 + 2 * SLOT;
    _Float16* S4 = S0 + 3 * SLOT;

    cvt_weights<<<dim3(256, 6), 256, 0, stream>>>(
        t_wq, t_wk, s_wk, t_wv, s_wv, s_wd, Wb);
    make_w2<<<256, 256, 0, stream>>>(s_wq, t_wd, t_bd, Wb + 5 * 65536, b2);

    // Qt -> S1, Kt -> S2, Vt -> S4 (all NL) in one dispatch
    gemm_trio<<<768, 512, 0, stream>>>(
        q, k, v, Wb + 0 * 65536, Wb + 1 * 65536, Wb + 3 * 65536, S1, S2, S4);

    attn_temporal<<<4096, 256, 0, stream>>>(S1, S2, S4, S0);   // Ot(NL) -> S0

    // fused: Qs/Ks/Vs projections + social attention + out-proj
    attn_social_fused<<<1024, 512, 0, stream>>>(
        S0, k, v, Wb + 5 * 65536, b2, Wb + 2 * 65536, Wb + 4 * 65536,
        Wb + 6 * 65536, s_bd, (float*)d_out);

    (void)in_sizes; (void)n_in; (void)out_size; (void)ws_size;
}